// Round 9
// baseline (625.122 us; speedup 1.0000x reference)
//
#include <hip/hip_runtime.h>
#include <hip/hip_bf16.h>

#define N_NODES 20000
#define N_EDGES 320000
#define TOT_E   (N_EDGES + N_NODES)   // 340000 with self loops
#define IN_CH   128
#define HEADS   8
#define CH      33
#define DD      264                   // HEADS*CH
#define OUTW    132
#define NEG     0.2f

#define LDB     272                   // bf16 payload row stride
#define LDA     288                   // hA bf16 row stride, K padded to 9*32
#define NT_HID  18                    // 17 payload tiles + 1 stats tile [was|wad]
#define NT_HEAD 12                    // head gemm tiles (132 -> 192, zero-padded)
#define NTG     6                     // compile-time tiles per y-group

typedef unsigned short ushort;
typedef short bf16x8 __attribute__((ext_vector_type(8)));
typedef float f32x4  __attribute__((ext_vector_type(4)));

__device__ inline void split2(float v, ushort& hi, ushort& lo) {
    __hip_bfloat16 h = __float2bfloat16(v);
    float r = v - __bfloat162float(h);
    __hip_bfloat16 l = __float2bfloat16(r);
    hi = *(ushort*)&h;
    lo = *(ushort*)&l;
}

__device__ inline float bf2f(ushort u) {
    union { unsigned int i; float f; } c;
    c.i = ((unsigned int)u) << 16;
    return c.f;
}

// ---------------- CSR build ----------------

__global__ void deg_k(const int* __restrict__ ei, int* __restrict__ deg) {
    int e = blockIdx.x * 256 + threadIdx.x;
    if (e >= TOT_E) return;
    int dst = (e < N_EDGES) ? ei[N_EDGES + e] : (e - N_EDGES);
    atomicAdd(&deg[dst], 1);
}

__global__ __launch_bounds__(1024) void scan_k(const int* __restrict__ deg,
                                               int* __restrict__ rowp) {
    __shared__ int part[1024];
    const int PER = 20;
    int t = threadIdx.x;
    int base = t * PER;
    int s = 0;
    for (int i = 0; i < PER; ++i) {
        int idx = base + i;
        if (idx < N_NODES) s += deg[idx];
    }
    part[t] = s;
    __syncthreads();
    for (int off = 1; off < 1024; off <<= 1) {
        int v = 0;
        if (t >= off) v = part[t - off];
        __syncthreads();
        part[t] += v;
        __syncthreads();
    }
    int run = part[t] - s;
    for (int i = 0; i < PER; ++i) {
        int idx = base + i;
        if (idx < N_NODES) { rowp[idx] = run; run += deg[idx]; }
    }
    if (t == 1023) rowp[N_NODES] = part[1023];
}

__global__ void fill_k(const int* __restrict__ ei, const int* __restrict__ rowp,
                       int* __restrict__ cur, int* __restrict__ csr) {
    int e = blockIdx.x * 256 + threadIdx.x;
    if (e >= TOT_E) return;
    int src, dst;
    if (e < N_EDGES) { src = ei[e]; dst = ei[N_EDGES + e]; }
    else             { src = dst = e - N_EDGES; }
    int p = atomicAdd(&cur[dst], 1);
    csr[rowp[dst] + p] = src;
}

// ---------------- input x -> bf16 (into hAhi, stride LDA) ----------------

__global__ void splitx_k(const float* __restrict__ x, ushort* __restrict__ ahi) {
    int idx = blockIdx.x * 256 + threadIdx.x;
    if (idx >= N_NODES * IN_CH) return;
    int n = idx >> 7, k = idx & 127;
    __hip_bfloat16 h = __float2bfloat16(x[idx]);
    ahi[(size_t)n * LDA + k] = *(ushort*)&h;
}

// ---------------- weight -> fragment-ordered hi/lo bf16 (+ optional stats tile) ------
// Wfrag[((p*NT + t)*64 + kq*16 + m)*8 + j] = V[p*32 + kq*8 + j][t*16 + m]
// last tile (when a_s given): col m<8 -> W·a_s per head m; m>=8 -> W·a_d per head m-8.

__global__ void convw_k(const float* __restrict__ W, const float* __restrict__ a_s,
                        const float* __restrict__ a_d, int K, int NC, int NT,
                        ushort* __restrict__ fhi, ushort* __restrict__ flo,
                        int total) {
    int gid = blockIdx.x * 256 + threadIdx.x;
    if (gid >= total) return;   // total = panels*NT*64
    int p = gid / (NT * 64);
    int rem = gid % (NT * 64);
    int t = rem >> 6, c = rem & 63;
    int kq = c >> 4, m = c & 15;
    int n = t * 16 + m;
    bool stats = (a_s != nullptr) && (t == NT - 1);
    ushort hi8[8], lo8[8];
#pragma unroll
    for (int j = 0; j < 8; ++j) {
        int k = p * 32 + kq * 8 + j;
        float v = 0.f;
        if (k < K) {
            if (stats) {
                const float* av = (m < 8) ? a_s : a_d;
                int h = (m < 8) ? m : m - 8;
                const float* wr = W + (size_t)k * NC + h * CH;
                float s = 0.f;
                for (int cc = 0; cc < CH; ++cc) s += wr[cc] * av[h * CH + cc];
                v = s;
            } else if (n < NC) {
                v = W[(size_t)k * NC + n];
            }
        }
        split2(v, hi8[j], lo8[j]);
    }
    size_t o = ((size_t)gid) * 8;
#pragma unroll
    for (int j = 0; j < 8; ++j) { fhi[o + j] = hi8[j]; flo[o + j] = lo8[j]; }
}

// ---------------- MFMA GEMM, M-tile 256, B via LDS, compile-time 6-tile group --------
// Wave w owns m-subtiles 4w..4w+3. Dynamic LDS: B (2*NTG*512) then A (16*512 per buf).
// Hidden (C==null): bf16 payload tiles<17, stats tile 17. Head: fp32 C + bias, 3-term.

__global__ __launch_bounds__(256) void gemm2_k(
    const ushort* __restrict__ Ahi, const ushort* __restrict__ Alo, int lda, int kpanels,
    const ushort* __restrict__ Bhi, const ushort* __restrict__ Blo, int NTtot,
    ushort* __restrict__ Cb16, float* __restrict__ as_, float* __restrict__ ad_,
    float* __restrict__ C, int ldc, int ncguard, const float* __restrict__ bias) {
    extern __shared__ ushort smem[];
    ushort* Bl = smem;                       // [hl][t][c*8] : 2*NTG*512
    ushort* Al = smem + 2 * NTG * 512;       // [hl][sub][chunk*8] : (use3?2:1)*16*512
    int tid = threadIdx.x;
    int m0 = blockIdx.x * 256;
    int t0 = blockIdx.y * NTG;
    bool use3 = (Alo != nullptr);

    f32x4 acc[4][NTG];
#pragma unroll
    for (int mt = 0; mt < 4; ++mt)
#pragma unroll
        for (int t = 0; t < NTG; ++t) acc[mt][t] = (f32x4){0.f, 0.f, 0.f, 0.f};

    int w = tid >> 6, lane = tid & 63;

    for (int p = 0; p < kpanels; ++p) {
        // stage A: 1024 (or 2048) 16-B chunks, coalesced 64-B rows
        int nA = use3 ? 2048 : 1024;
        for (int id = tid; id < nA; id += 256) {
            int hl = id >> 10;
            int cid = id & 1023;
            int mrow = cid >> 2, kq = cid & 3;
            int gm = m0 + mrow;
            uint4 v = {0, 0, 0, 0};
            if (gm < N_NODES) {
                const ushort* src = (hl ? Alo : Ahi) + (size_t)gm * lda + p * 32 + kq * 8;
                v = *(const uint4*)src;
            }
            *(uint4*)&Al[((hl * 16 + (mrow >> 4)) * 512) + (kq * 16 + (mrow & 15)) * 8] = v;
        }
        // stage B: 2*NTG*64 = 768 contiguous 16-B chunks
        for (int id = tid; id < 2 * NTG * 64; id += 256) {
            int hl = id / (NTG * 64);
            int rem = id % (NTG * 64);
            int t = rem >> 6, c = rem & 63;
            const ushort* src = (hl ? Blo : Bhi) + ((size_t)(p * NTtot + t0 + t) * 64 + c) * 8;
            *(uint4*)&Bl[((hl * NTG + t) * 512) + c * 8] = *(const uint4*)src;
        }
        __syncthreads();

        bf16x8 a[4], l[4];
#pragma unroll
        for (int mt = 0; mt < 4; ++mt) {
            a[mt] = *(const bf16x8*)&Al[((4 * w + mt) * 512) + lane * 8];
            if (use3) l[mt] = *(const bf16x8*)&Al[((16 + 4 * w + mt) * 512) + lane * 8];
        }
#pragma unroll
        for (int t = 0; t < NTG; ++t) {
            bf16x8 bh = *(const bf16x8*)&Bl[(t * 512) + lane * 8];
            bf16x8 bl = *(const bf16x8*)&Bl[((NTG + t) * 512) + lane * 8];
#pragma unroll
            for (int mt = 0; mt < 4; ++mt) {
                acc[mt][t] = __builtin_amdgcn_mfma_f32_16x16x32_bf16(a[mt], bh, acc[mt][t], 0, 0, 0);
                acc[mt][t] = __builtin_amdgcn_mfma_f32_16x16x32_bf16(a[mt], bl, acc[mt][t], 0, 0, 0);
                if (use3)
                    acc[mt][t] = __builtin_amdgcn_mfma_f32_16x16x32_bf16(l[mt], bh, acc[mt][t], 0, 0, 0);
            }
        }
        __syncthreads();
    }

    // store: C/D layout col = lane&15, row = (lane>>4)*4 + r
    int col = lane & 15;
#pragma unroll
    for (int mt = 0; mt < 4; ++mt) {
        int rbase = m0 + (4 * w + mt) * 16 + ((lane >> 4) << 2);
#pragma unroll
        for (int t = 0; t < NTG; ++t) {
            int tg = t0 + t;
#pragma unroll
            for (int r = 0; r < 4; ++r) {
                int gm = rbase + r;
                if (gm >= N_NODES) continue;
                float v = acc[mt][t][r];
                if (C) {
                    int gn = tg * 16 + col;
                    if (gn < ncguard) C[(size_t)gm * ldc + gn] = v + bias[gn];
                } else if (tg < 17) {
                    __hip_bfloat16 bv = __float2bfloat16(v);
                    Cb16[(size_t)gm * LDB + tg * 16 + col] = *(ushort*)&bv;
                } else {
                    if (col < 8) as_[(size_t)gm * 8 + col] = v;
                    else         ad_[(size_t)gm * 8 + col - 8] = v;
                }
            }
        }
    }
}

// ---------------- fused softmax + gather-aggregate ----------------

__global__ __launch_bounds__(256) void gat_k(
    const ushort* __restrict__ xb, const float* __restrict__ as_,
    const float* __restrict__ ad_, const int* __restrict__ rowp,
    const int* __restrict__ csr, const float* __restrict__ bias,
    ushort* __restrict__ outhi, ushort* __restrict__ outlo) {
    int wv = threadIdx.x >> 6, lane = threadIdx.x & 63;
    int node = blockIdx.x * 4 + wv;   // grid is exactly N/4
    int r0 = rowp[node], dg = rowp[node + 1] - r0;

    __shared__ float lex[4][64][9];   // inner dim 9: conflict-free staging writes
    __shared__ int   lsrc[4][64];
    __shared__ int   bdg[4];

    if (lane == 0) bdg[wv] = dg;
    __syncthreads();
    int bmax = max(max(bdg[0], bdg[1]), max(bdg[2], bdg[3]));
    int nchunks = (bmax + 63) >> 6;

    float ad[8];
#pragma unroll
    for (int h = 0; h < 8; ++h) ad[h] = ad_[node * 8 + h];

    float mx[8], iv[8], e8[8];
    int myS = node;
    bool fast = (dg <= 64);
    if (fast) {
#pragma unroll
        for (int h = 0; h < 8; ++h) e8[h] = -1e30f;
        if (lane < dg) {
            myS = csr[r0 + lane];
            const float* ap = as_ + (size_t)myS * 8;
#pragma unroll
            for (int h = 0; h < 8; ++h) {
                float e = ap[h] + ad[h];
                e8[h] = e > 0.f ? e : NEG * e;
            }
        }
#pragma unroll
        for (int h = 0; h < 8; ++h) {
            float m = e8[h];
            for (int off = 32; off; off >>= 1) m = fmaxf(m, __shfl_xor(m, off, 64));
            mx[h] = m;
        }
#pragma unroll
        for (int h = 0; h < 8; ++h) {
            float ex = (lane < dg) ? __expf(e8[h] - mx[h]) : 0.f;
            e8[h] = ex;
            float s = ex;
            for (int off = 32; off; off >>= 1) s += __shfl_xor(s, off, 64);
            iv[h] = 1.0f / (s + 1e-16f);
        }
    } else {
#pragma unroll
        for (int h = 0; h < 8; ++h) mx[h] = -1e30f;
        for (int j = lane; j < dg; j += 64) {
            int s = csr[r0 + j];
            const float* ap = as_ + (size_t)s * 8;
#pragma unroll
            for (int h = 0; h < 8; ++h) {
                float e = ap[h] + ad[h];
                e = e > 0.f ? e : NEG * e;
                mx[h] = fmaxf(mx[h], e);
            }
        }
#pragma unroll
        for (int h = 0; h < 8; ++h)
            for (int off = 32; off; off >>= 1)
                mx[h] = fmaxf(mx[h], __shfl_xor(mx[h], off, 64));
        float sm[8] = {0.f, 0.f, 0.f, 0.f, 0.f, 0.f, 0.f, 0.f};
        for (int j = lane; j < dg; j += 64) {
            int s = csr[r0 + j];
            const float* ap = as_ + (size_t)s * 8;
#pragma unroll
            for (int h = 0; h < 8; ++h) {
                float e = ap[h] + ad[h];
                e = e > 0.f ? e : NEG * e;
                sm[h] += __expf(e - mx[h]);
            }
        }
#pragma unroll
        for (int h = 0; h < 8; ++h) {
            for (int off = 32; off; off >>= 1) sm[h] += __shfl_xor(sm[h], off, 64);
            iv[h] = 1.0f / (sm[h] + 1e-16f);
        }
    }

    int h0[4], h1[4];
#pragma unroll
    for (int j = 0; j < 4; ++j) {
        h0[j] = (4 * lane + j) / 33;
        h1[j] = (4 * (lane + 64) + j) / 33;   // lanes 0,1 only (always head 7)
    }
    float4 a0 = {0.f, 0.f, 0.f, 0.f}, a1 = {0.f, 0.f, 0.f, 0.f};

    for (int c = 0; c < nchunks; ++c) {
        int base = c << 6, j = base + lane;
        __syncthreads();
        int s = node;
        float al[8];
#pragma unroll
        for (int h = 0; h < 8; ++h) al[h] = 0.f;
        if (j < dg) {
            if (fast) {
                s = myS;
#pragma unroll
                for (int h = 0; h < 8; ++h) al[h] = e8[h] * iv[h];
            } else {
                s = csr[r0 + j];
                const float* ap = as_ + (size_t)s * 8;
#pragma unroll
                for (int h = 0; h < 8; ++h) {
                    float e = ap[h] + ad[h];
                    e = e > 0.f ? e : NEG * e;
                    al[h] = __expf(e - mx[h]) * iv[h];
                }
            }
        }
        lsrc[wv][lane] = s;
#pragma unroll
        for (int h = 0; h < 8; ++h) lex[wv][lane][h] = al[h];
        __syncthreads();

        int rem = dg - base;
        int cnt = rem > 64 ? 64 : (rem < 0 ? 0 : rem);
        int cnt4 = (cnt + 3) & ~3;
        for (int jj = 0; jj < cnt4; jj += 4) {
            int s0 = lsrc[wv][jj + 0], s1 = lsrc[wv][jj + 1];
            int s2 = lsrc[wv][jj + 2], s3 = lsrc[wv][jj + 3];
            const ushort4* p0 = (const ushort4*)(xb + (size_t)s0 * LDB);
            const ushort4* p1 = (const ushort4*)(xb + (size_t)s1 * LDB);
            const ushort4* p2 = (const ushort4*)(xb + (size_t)s2 * LDB);
            const ushort4* p3 = (const ushort4*)(xb + (size_t)s3 * LDB);
            ushort4 v0 = p0[lane], v1 = p1[lane], v2 = p2[lane], v3 = p3[lane];
            ushort4 w0, w1, w2, w3;
            if (lane < 2) { w0 = p0[64 + lane]; w1 = p1[64 + lane]; w2 = p2[64 + lane]; w3 = p3[64 + lane]; }
            const float* x0 = lex[wv][jj + 0];
            const float* x1 = lex[wv][jj + 1];
            const float* x2 = lex[wv][jj + 2];
            const float* x3 = lex[wv][jj + 3];
            a0.x += x0[h0[0]] * bf2f(v0.x) + x1[h0[0]] * bf2f(v1.x)
                  + x2[h0[0]] * bf2f(v2.x) + x3[h0[0]] * bf2f(v3.x);
            a0.y += x0[h0[1]] * bf2f(v0.y) + x1[h0[1]] * bf2f(v1.y)
                  + x2[h0[1]] * bf2f(v2.y) + x3[h0[1]] * bf2f(v3.y);
            a0.z += x0[h0[2]] * bf2f(v0.z) + x1[h0[2]] * bf2f(v1.z)
                  + x2[h0[2]] * bf2f(v2.z) + x3[h0[2]] * bf2f(v3.z);
            a0.w += x0[h0[3]] * bf2f(v0.w) + x1[h0[3]] * bf2f(v1.w)
                  + x2[h0[3]] * bf2f(v2.w) + x3[h0[3]] * bf2f(v3.w);
            if (lane < 2) {
                a1.x += x0[h1[0]] * bf2f(w0.x) + x1[h1[0]] * bf2f(w1.x)
                      + x2[h1[0]] * bf2f(w2.x) + x3[h1[0]] * bf2f(w3.x);
                a1.y += x0[h1[1]] * bf2f(w0.y) + x1[h1[1]] * bf2f(w1.y)
                      + x2[h1[1]] * bf2f(w2.y) + x3[h1[1]] * bf2f(w3.y);
                a1.z += x0[h1[2]] * bf2f(w0.z) + x1[h1[2]] * bf2f(w1.z)
                      + x2[h1[2]] * bf2f(w2.z) + x3[h1[2]] * bf2f(w3.z);
                a1.w += x0[h1[3]] * bf2f(w0.w) + x1[h1[3]] * bf2f(w1.w)
                      + x2[h1[3]] * bf2f(w2.w) + x3[h1[3]] * bf2f(w3.w);
            }
        }
    }

    // epilogue: bias + elu, bf16 (hi) out; lo only when requested (head-gemm input)
#pragma unroll
    for (int k = 0; k < 2; ++k) {
        int i4 = lane + 64 * k;
        if (i4 < 66) {
            float4 a = (k == 0) ? a0 : a1;
            float vals[4] = {a.x, a.y, a.z, a.w};
            ushort hi4[4], lo4[4];
#pragma unroll
            for (int j = 0; j < 4; ++j) {
                float v = vals[j] + bias[i4 * 4 + j];
                v = v > 0.f ? v : (__expf(v) - 1.f);
                split2(v, hi4[j], lo4[j]);
            }
            size_t o = (size_t)node * LDA + i4 * 4;
            *(ushort4*)(outhi + o) = *(ushort4*)hi4;
            if (outlo) *(ushort4*)(outlo + o) = *(ushort4*)lo4;
        } else if (i4 < 72) {
            ushort4 z = {0, 0, 0, 0};
            size_t o = (size_t)node * LDA + i4 * 4;
            *(ushort4*)(outhi + o) = z;
            if (outlo) *(ushort4*)(outlo + o) = z;
        }
    }
}

// ---------------- launch ----------------

extern "C" void kernel_launch(void* const* d_in, const int* in_sizes, int n_in,
                              void* d_out, int out_size, void* d_ws, size_t ws_size,
                              hipStream_t stream) {
    const float* x  = (const float*)d_in[0];
    const int*   ei = (const int*)d_in[1];
    const float* W[4]  = {(const float*)d_in[2],  (const float*)d_in[6],
                          (const float*)d_in[10], (const float*)d_in[14]};
    const float* As[4] = {(const float*)d_in[3],  (const float*)d_in[7],
                          (const float*)d_in[11], (const float*)d_in[15]};
    const float* Ad[4] = {(const float*)d_in[4],  (const float*)d_in[8],
                          (const float*)d_in[12], (const float*)d_in[16]};
    const float* Bb[4] = {(const float*)d_in[5],  (const float*)d_in[9],
                          (const float*)d_in[13], (const float*)d_in[17]};
    const float* Wh = (const float*)d_in[18];
    const float* bh = (const float*)d_in[19];

    // ---- workspace carve ----
    char* p = (char*)d_ws;
    ushort* hBb  = (ushort*)p;          p += (size_t)N_NODES * LDB * 2;      // xh bf16 payload
    ushort* hAhi = (ushort*)p;          p += (size_t)N_NODES * LDA * 2;      // A hi
    ushort* hAlo = (ushort*)p;          p += (size_t)N_NODES * LDA * 2;      // A lo (layer-3 only)
    float* as_  = (float*)p;            p += (size_t)N_NODES * HEADS * 4;
    float* ad_  = (float*)p;            p += (size_t)N_NODES * HEADS * 4;
    const int wsz0 = 4 * NT_HID * 512;   // layer-0: 4 k-panels
    const int wszH = 9 * NT_HID * 512;   // layers 1-3: 9 k-panels
    const int wszO = 9 * NT_HEAD * 512;  // head (12 tiles incl. zero pad)
    ushort* wfhi[4]; ushort* wflo[4];
    for (int l = 0; l < 4; ++l) {
        int sz = (l == 0) ? wsz0 : wszH;
        wfhi[l] = (ushort*)p; p += (size_t)sz * 2;
        wflo[l] = (ushort*)p; p += (size_t)sz * 2;
    }
    ushort* whhi = (ushort*)p; p += (size_t)wszO * 2;
    ushort* whlo = (ushort*)p; p += (size_t)wszO * 2;
    int* deg  = (int*)p;  p += N_NODES * 4;
    int* cur  = (int*)p;  p += N_NODES * 4;
    int* rowp = (int*)p;  p += (N_NODES + 1) * 4;
    int* csr  = (int*)p;  p += (size_t)TOT_E * 4;

    // ---- CSR build ----
    hipMemsetAsync(deg, 0, sizeof(int) * 2 * N_NODES, stream);  // deg + cur
    int egrid = (TOT_E + 255) / 256;
    deg_k<<<egrid, 256, 0, stream>>>(ei, deg);
    scan_k<<<1, 1024, 0, stream>>>(deg, rowp);
    fill_k<<<egrid, 256, 0, stream>>>(ei, rowp, cur, csr);

    // ---- weight + input conversion ----
    splitx_k<<<(N_NODES * IN_CH + 255) / 256, 256, 0, stream>>>(x, hAhi);
    {
        int tot = 4 * NT_HID * 64;
        convw_k<<<(tot + 255) / 256, 256, 0, stream>>>(W[0], As[0], Ad[0], IN_CH, DD,
                                                       NT_HID, wfhi[0], wflo[0], tot);
    }
    for (int l = 1; l < 4; ++l) {
        int tot = 9 * NT_HID * 64;
        convw_k<<<(tot + 255) / 256, 256, 0, stream>>>(W[l], As[l], Ad[l], DD, DD,
                                                       NT_HID, wfhi[l], wflo[l], tot);
    }
    {
        int tot = 9 * NT_HEAD * 64;
        convw_k<<<(tot + 255) / 256, 256, 0, stream>>>(Wh, nullptr, nullptr, DD, OUTW,
                                                       NT_HEAD, whhi, whlo, tot);
    }

    dim3 gG((N_NODES + 255) / 256, NT_HID / NTG);   // 79 x 3
    dim3 gO((N_NODES + 255) / 256, NT_HEAD / NTG);  // 79 x 2
    size_t ldsHid = (2 * NTG * 512 + 16 * 512) * sizeof(ushort);       // 28 KB
    size_t ldsHead = (2 * NTG * 512 + 2 * 16 * 512) * sizeof(ushort);  // 44 KB
    int ggrid = N_NODES / 4;                        // 5000, exact

    for (int l = 0; l < 4; ++l) {
        int kp = (l == 0) ? 4 : 9;
        gemm2_k<<<gG, 256, ldsHid, stream>>>(hAhi, nullptr, LDA, kp,
                                             wfhi[l], wflo[l], NT_HID,
                                             hBb, as_, ad_, nullptr, 0, 0, nullptr);
        gat_k<<<ggrid, 256, 0, stream>>>(hBb, as_, ad_, rowp, csr, Bb[l],
                                         hAhi, (l == 3) ? hAlo : nullptr);
    }

    // head readout (3-term for output precision) -> fp32 out [N, 132]
    gemm2_k<<<gO, 256, ldsHead, stream>>>(hAhi, hAlo, LDA, 9,
                                          whhi, whlo, NT_HEAD,
                                          nullptr, nullptr, nullptr,
                                          (float*)d_out, OUTW, OUTW, bh);
}

// Round 10
// 548.849 us; speedup vs baseline: 1.1390x; 1.1390x over previous
//
#include <hip/hip_runtime.h>
#include <hip/hip_bf16.h>

#define N_NODES 20000
#define N_EDGES 320000
#define TOT_E   (N_EDGES + N_NODES)   // 340000 with self loops
#define IN_CH   128
#define HEADS   8
#define CH      33
#define DD      264                   // HEADS*CH
#define OUTW    132
#define NEG     0.2f

#define LDB     272                   // bf16 payload row stride
#define LDA     320                   // hA bf16 row stride, K padded to 10*32 (pairs of panels)
#define NT_HID  18                    // 17 payload tiles + 1 stats tile [was|wad]
#define NT_HEAD 12                    // head gemm tiles (132 -> 192, zero-padded)
#define NTG     6                     // compile-time tiles per y-group

typedef unsigned short ushort;
typedef short bf16x8 __attribute__((ext_vector_type(8)));
typedef float f32x4  __attribute__((ext_vector_type(4)));

__device__ inline void split2(float v, ushort& hi, ushort& lo) {
    __hip_bfloat16 h = __float2bfloat16(v);
    float r = v - __bfloat162float(h);
    __hip_bfloat16 l = __float2bfloat16(r);
    hi = *(ushort*)&h;
    lo = *(ushort*)&l;
}

__device__ inline float bf2f(ushort u) {
    union { unsigned int i; float f; } c;
    c.i = ((unsigned int)u) << 16;
    return c.f;
}

// ---------------- CSR build ----------------

__global__ void deg_k(const int* __restrict__ ei, int* __restrict__ deg) {
    int e = blockIdx.x * 256 + threadIdx.x;
    if (e >= TOT_E) return;
    int dst = (e < N_EDGES) ? ei[N_EDGES + e] : (e - N_EDGES);
    atomicAdd(&deg[dst], 1);
}

__global__ __launch_bounds__(1024) void scan_k(const int* __restrict__ deg,
                                               int* __restrict__ rowp) {
    __shared__ int part[1024];
    const int PER = 20;
    int t = threadIdx.x;
    int base = t * PER;
    int s = 0;
    for (int i = 0; i < PER; ++i) {
        int idx = base + i;
        if (idx < N_NODES) s += deg[idx];
    }
    part[t] = s;
    __syncthreads();
    for (int off = 1; off < 1024; off <<= 1) {
        int v = 0;
        if (t >= off) v = part[t - off];
        __syncthreads();
        part[t] += v;
        __syncthreads();
    }
    int run = part[t] - s;
    for (int i = 0; i < PER; ++i) {
        int idx = base + i;
        if (idx < N_NODES) { rowp[idx] = run; run += deg[idx]; }
    }
    if (t == 1023) rowp[N_NODES] = part[1023];
}

__global__ void fill_k(const int* __restrict__ ei, const int* __restrict__ rowp,
                       int* __restrict__ cur, int* __restrict__ csr) {
    int e = blockIdx.x * 256 + threadIdx.x;
    if (e >= TOT_E) return;
    int src, dst;
    if (e < N_EDGES) { src = ei[e]; dst = ei[N_EDGES + e]; }
    else             { src = dst = e - N_EDGES; }
    int p = atomicAdd(&cur[dst], 1);
    csr[rowp[dst] + p] = src;
}

// ---------------- input x -> bf16 (into hAhi, stride LDA) ----------------

__global__ void splitx_k(const float* __restrict__ x, ushort* __restrict__ ahi) {
    int idx = blockIdx.x * 256 + threadIdx.x;
    if (idx >= N_NODES * IN_CH) return;
    int n = idx >> 7, k = idx & 127;
    __hip_bfloat16 h = __float2bfloat16(x[idx]);
    ahi[(size_t)n * LDA + k] = *(ushort*)&h;
}

// ---------------- weight -> fragment-ordered hi/lo bf16 (+ optional stats tile) ------
// Wfrag[((p*NT + t)*64 + kq*16 + m)*8 + j] = V[p*32 + kq*8 + j][t*16 + m]
// last tile (when a_s given): col m<8 -> W·a_s per head m; m>=8 -> W·a_d per head m-8.

__global__ void convw_k(const float* __restrict__ W, const float* __restrict__ a_s,
                        const float* __restrict__ a_d, int K, int NC, int NT,
                        ushort* __restrict__ fhi, ushort* __restrict__ flo,
                        int total) {
    int gid = blockIdx.x * 256 + threadIdx.x;
    if (gid >= total) return;   // total = panels*NT*64
    int p = gid / (NT * 64);
    int rem = gid % (NT * 64);
    int t = rem >> 6, c = rem & 63;
    int kq = c >> 4, m = c & 15;
    int n = t * 16 + m;
    bool stats = (a_s != nullptr) && (t == NT - 1);
    ushort hi8[8], lo8[8];
#pragma unroll
    for (int j = 0; j < 8; ++j) {
        int k = p * 32 + kq * 8 + j;
        float v = 0.f;
        if (k < K) {
            if (stats) {
                const float* av = (m < 8) ? a_s : a_d;
                int h = (m < 8) ? m : m - 8;
                const float* wr = W + (size_t)k * NC + h * CH;
                float s = 0.f;
                for (int cc = 0; cc < CH; ++cc) s += wr[cc] * av[h * CH + cc];
                v = s;
            } else if (n < NC) {
                v = W[(size_t)k * NC + n];
            }
        }
        split2(v, hi8[j], lo8[j]);
    }
    size_t o = ((size_t)gid) * 8;
#pragma unroll
    for (int j = 0; j < 8; ++j) { fhi[o + j] = hi8[j]; flo[o + j] = lo8[j]; }
}

// ---------------- MFMA GEMM, M=128, BK=64 (2 panels/barrier), swizzled A LDS --------
// Wave w owns m-subtiles 2w, 2w+1. A LDS chunk c stored at c ^ ((c>>4)<<1) to make
// staging writes conflict-free while reads stay 2-way (free).
// Hidden (USE3=0, C==null): bf16 payload tiles<17, stats tile 17. Head: fp32 C+bias.

template<bool USE3>
__global__ __launch_bounds__(256) void gemm3_k(
    const ushort* __restrict__ Ahi, const ushort* __restrict__ Alo, int kpairs,
    const ushort* __restrict__ Bhi, const ushort* __restrict__ Blo, int NTtot,
    ushort* __restrict__ Cb16, float* __restrict__ as_, float* __restrict__ ad_,
    float* __restrict__ C, int ldc, int ncguard, const float* __restrict__ bias) {
    __shared__ ushort Al[USE3 ? 2 : 1][2][8][512];  // [hl][panel][m-subtile][chunk*8]
    __shared__ ushort Bl[2][2][NTG][512];           // [hl][panel][t][chunk*8]
    int tid = threadIdx.x;
    int m0 = blockIdx.x * 128;
    int t0 = blockIdx.y * NTG;

    f32x4 acc[2][NTG];
#pragma unroll
    for (int mt = 0; mt < 2; ++mt)
#pragma unroll
        for (int t = 0; t < NTG; ++t) acc[mt][t] = (f32x4){0.f, 0.f, 0.f, 0.f};

    int w = tid >> 6, lane = tid & 63;
    int csA = (lane ^ ((lane >> 4) << 1)) * 8;   // swizzled A read offset

    for (int pp = 0; pp < kpairs; ++pp) {
        // stage A: 2 panels = 128 B/row contiguous; 1024 chunks per hl
        int nA = USE3 ? 2048 : 1024;
        for (int id = tid; id < nA; id += 256) {
            int hl = id >> 10;
            int cid = id & 1023;
            int mrow = cid >> 3, kq8 = cid & 7;       // kq8: panel*4 + kq
            int panel = kq8 >> 2, kq = kq8 & 3;
            int gm = m0 + mrow;
            uint4 v = {0, 0, 0, 0};
            if (gm < N_NODES) {
                const ushort* src = (hl ? Alo : Ahi) + (size_t)gm * LDA + pp * 64 + kq8 * 8;
                v = *(const uint4*)src;
            }
            int c = kq * 16 + (mrow & 15);
            int cs = c ^ ((c >> 4) << 1);             // swizzle
            *(uint4*)&Al[hl][panel][mrow >> 4][cs * 8] = v;
        }
        // stage B: 2 hl x 2 panels x NTG tiles x 64 chunks (natural order, conflict-free)
        for (int id = tid; id < 2 * 2 * NTG * 64; id += 256) {
            int c = id & 63;
            int r = id >> 6;
            int t = r % NTG; r /= NTG;
            int panel = r & 1;
            int hl = r >> 1;
            const ushort* src = (hl ? Blo : Bhi)
                + ((size_t)((pp * 2 + panel) * NTtot + t0 + t) * 64 + c) * 8;
            *(uint4*)&Bl[hl][panel][t][c * 8] = *(const uint4*)src;
        }
        __syncthreads();

#pragma unroll
        for (int panel = 0; panel < 2; ++panel) {
            bf16x8 a0 = *(const bf16x8*)&Al[0][panel][2 * w][csA];
            bf16x8 a1 = *(const bf16x8*)&Al[0][panel][2 * w + 1][csA];
            bf16x8 l0, l1;
            if (USE3) {
                l0 = *(const bf16x8*)&Al[1][panel][2 * w][csA];
                l1 = *(const bf16x8*)&Al[1][panel][2 * w + 1][csA];
            }
#pragma unroll
            for (int t = 0; t < NTG; ++t) {
                bf16x8 bh = *(const bf16x8*)&Bl[0][panel][t][lane * 8];
                bf16x8 bl = *(const bf16x8*)&Bl[1][panel][t][lane * 8];
                acc[0][t] = __builtin_amdgcn_mfma_f32_16x16x32_bf16(a0, bh, acc[0][t], 0, 0, 0);
                acc[1][t] = __builtin_amdgcn_mfma_f32_16x16x32_bf16(a1, bh, acc[1][t], 0, 0, 0);
                acc[0][t] = __builtin_amdgcn_mfma_f32_16x16x32_bf16(a0, bl, acc[0][t], 0, 0, 0);
                acc[1][t] = __builtin_amdgcn_mfma_f32_16x16x32_bf16(a1, bl, acc[1][t], 0, 0, 0);
                if (USE3) {
                    acc[0][t] = __builtin_amdgcn_mfma_f32_16x16x32_bf16(l0, bh, acc[0][t], 0, 0, 0);
                    acc[1][t] = __builtin_amdgcn_mfma_f32_16x16x32_bf16(l1, bh, acc[1][t], 0, 0, 0);
                }
            }
        }
        __syncthreads();
    }

    // store: C/D layout col = lane&15, row = (lane>>4)*4 + r
    int col = lane & 15;
#pragma unroll
    for (int mt = 0; mt < 2; ++mt) {
        int rbase = m0 + (2 * w + mt) * 16 + ((lane >> 4) << 2);
#pragma unroll
        for (int t = 0; t < NTG; ++t) {
            int tg = t0 + t;
#pragma unroll
            for (int r = 0; r < 4; ++r) {
                int gm = rbase + r;
                if (gm >= N_NODES) continue;
                float v = acc[mt][t][r];
                if (C) {
                    int gn = tg * 16 + col;
                    if (gn < ncguard) C[(size_t)gm * ldc + gn] = v + bias[gn];
                } else if (tg < 17) {
                    __hip_bfloat16 bv = __float2bfloat16(v);
                    Cb16[(size_t)gm * LDB + tg * 16 + col] = *(ushort*)&bv;
                } else {
                    if (col < 8) as_[(size_t)gm * 8 + col] = v;
                    else         ad_[(size_t)gm * 8 + col - 8] = v;
                }
            }
        }
    }
}

// ---------------- fused softmax + gather-aggregate ----------------

__global__ __launch_bounds__(256) void gat_k(
    const ushort* __restrict__ xb, const float* __restrict__ as_,
    const float* __restrict__ ad_, const int* __restrict__ rowp,
    const int* __restrict__ csr, const float* __restrict__ bias,
    ushort* __restrict__ outhi, ushort* __restrict__ outlo) {
    int wv = threadIdx.x >> 6, lane = threadIdx.x & 63;
    int node = blockIdx.x * 4 + wv;   // grid is exactly N/4
    int r0 = rowp[node], dg = rowp[node + 1] - r0;

    __shared__ float lex[4][64][9];   // inner dim 9: conflict-free staging writes
    __shared__ int   lsrc[4][64];
    __shared__ int   bdg[4];

    if (lane == 0) bdg[wv] = dg;
    __syncthreads();
    int bmax = max(max(bdg[0], bdg[1]), max(bdg[2], bdg[3]));
    int nchunks = (bmax + 63) >> 6;

    float ad[8];
#pragma unroll
    for (int h = 0; h < 8; ++h) ad[h] = ad_[node * 8 + h];

    float mx[8], iv[8], e8[8];
    int myS = node;
    bool fast = (dg <= 64);
    if (fast) {
#pragma unroll
        for (int h = 0; h < 8; ++h) e8[h] = -1e30f;
        if (lane < dg) {
            myS = csr[r0 + lane];
            const float* ap = as_ + (size_t)myS * 8;
#pragma unroll
            for (int h = 0; h < 8; ++h) {
                float e = ap[h] + ad[h];
                e8[h] = e > 0.f ? e : NEG * e;
            }
        }
#pragma unroll
        for (int h = 0; h < 8; ++h) {
            float m = e8[h];
            for (int off = 32; off; off >>= 1) m = fmaxf(m, __shfl_xor(m, off, 64));
            mx[h] = m;
        }
#pragma unroll
        for (int h = 0; h < 8; ++h) {
            float ex = (lane < dg) ? __expf(e8[h] - mx[h]) : 0.f;
            e8[h] = ex;
            float s = ex;
            for (int off = 32; off; off >>= 1) s += __shfl_xor(s, off, 64);
            iv[h] = 1.0f / (s + 1e-16f);
        }
    } else {
#pragma unroll
        for (int h = 0; h < 8; ++h) mx[h] = -1e30f;
        for (int j = lane; j < dg; j += 64) {
            int s = csr[r0 + j];
            const float* ap = as_ + (size_t)s * 8;
#pragma unroll
            for (int h = 0; h < 8; ++h) {
                float e = ap[h] + ad[h];
                e = e > 0.f ? e : NEG * e;
                mx[h] = fmaxf(mx[h], e);
            }
        }
#pragma unroll
        for (int h = 0; h < 8; ++h)
            for (int off = 32; off; off >>= 1)
                mx[h] = fmaxf(mx[h], __shfl_xor(mx[h], off, 64));
        float sm[8] = {0.f, 0.f, 0.f, 0.f, 0.f, 0.f, 0.f, 0.f};
        for (int j = lane; j < dg; j += 64) {
            int s = csr[r0 + j];
            const float* ap = as_ + (size_t)s * 8;
#pragma unroll
            for (int h = 0; h < 8; ++h) {
                float e = ap[h] + ad[h];
                e = e > 0.f ? e : NEG * e;
                sm[h] += __expf(e - mx[h]);
            }
        }
#pragma unroll
        for (int h = 0; h < 8; ++h) {
            for (int off = 32; off; off >>= 1) sm[h] += __shfl_xor(sm[h], off, 64);
            iv[h] = 1.0f / (sm[h] + 1e-16f);
        }
    }

    int h0[4], h1[4];
#pragma unroll
    for (int j = 0; j < 4; ++j) {
        h0[j] = (4 * lane + j) / 33;
        h1[j] = (4 * (lane + 64) + j) / 33;   // lanes 0,1 only (always head 7)
    }
    float4 a0 = {0.f, 0.f, 0.f, 0.f}, a1 = {0.f, 0.f, 0.f, 0.f};

    for (int c = 0; c < nchunks; ++c) {
        int base = c << 6, j = base + lane;
        __syncthreads();
        int s = node;
        float al[8];
#pragma unroll
        for (int h = 0; h < 8; ++h) al[h] = 0.f;
        if (j < dg) {
            if (fast) {
                s = myS;
#pragma unroll
                for (int h = 0; h < 8; ++h) al[h] = e8[h] * iv[h];
            } else {
                s = csr[r0 + j];
                const float* ap = as_ + (size_t)s * 8;
#pragma unroll
                for (int h = 0; h < 8; ++h) {
                    float e = ap[h] + ad[h];
                    e = e > 0.f ? e : NEG * e;
                    al[h] = __expf(e - mx[h]) * iv[h];
                }
            }
        }
        lsrc[wv][lane] = s;
#pragma unroll
        for (int h = 0; h < 8; ++h) lex[wv][lane][h] = al[h];
        __syncthreads();

        int rem = dg - base;
        int cnt = rem > 64 ? 64 : (rem < 0 ? 0 : rem);
        int cnt4 = (cnt + 3) & ~3;
        for (int jj = 0; jj < cnt4; jj += 4) {
            int s0 = lsrc[wv][jj + 0], s1 = lsrc[wv][jj + 1];
            int s2 = lsrc[wv][jj + 2], s3 = lsrc[wv][jj + 3];
            const ushort4* p0 = (const ushort4*)(xb + (size_t)s0 * LDB);
            const ushort4* p1 = (const ushort4*)(xb + (size_t)s1 * LDB);
            const ushort4* p2 = (const ushort4*)(xb + (size_t)s2 * LDB);
            const ushort4* p3 = (const ushort4*)(xb + (size_t)s3 * LDB);
            ushort4 v0 = p0[lane], v1 = p1[lane], v2 = p2[lane], v3 = p3[lane];
            ushort4 w0, w1, w2, w3;
            if (lane < 2) { w0 = p0[64 + lane]; w1 = p1[64 + lane]; w2 = p2[64 + lane]; w3 = p3[64 + lane]; }
            const float* x0 = lex[wv][jj + 0];
            const float* x1 = lex[wv][jj + 1];
            const float* x2 = lex[wv][jj + 2];
            const float* x3 = lex[wv][jj + 3];
            a0.x += x0[h0[0]] * bf2f(v0.x) + x1[h0[0]] * bf2f(v1.x)
                  + x2[h0[0]] * bf2f(v2.x) + x3[h0[0]] * bf2f(v3.x);
            a0.y += x0[h0[1]] * bf2f(v0.y) + x1[h0[1]] * bf2f(v1.y)
                  + x2[h0[1]] * bf2f(v2.y) + x3[h0[1]] * bf2f(v3.y);
            a0.z += x0[h0[2]] * bf2f(v0.z) + x1[h0[2]] * bf2f(v1.z)
                  + x2[h0[2]] * bf2f(v2.z) + x3[h0[2]] * bf2f(v3.z);
            a0.w += x0[h0[3]] * bf2f(v0.w) + x1[h0[3]] * bf2f(v1.w)
                  + x2[h0[3]] * bf2f(v2.w) + x3[h0[3]] * bf2f(v3.w);
            if (lane < 2) {
                a1.x += x0[h1[0]] * bf2f(w0.x) + x1[h1[0]] * bf2f(w1.x)
                      + x2[h1[0]] * bf2f(w2.x) + x3[h1[0]] * bf2f(w3.x);
                a1.y += x0[h1[1]] * bf2f(w0.y) + x1[h1[1]] * bf2f(w1.y)
                      + x2[h1[1]] * bf2f(w2.y) + x3[h1[1]] * bf2f(w3.y);
                a1.z += x0[h1[2]] * bf2f(w0.z) + x1[h1[2]] * bf2f(w1.z)
                      + x2[h1[2]] * bf2f(w2.z) + x3[h1[2]] * bf2f(w3.z);
                a1.w += x0[h1[3]] * bf2f(w0.w) + x1[h1[3]] * bf2f(w1.w)
                      + x2[h1[3]] * bf2f(w2.w) + x3[h1[3]] * bf2f(w3.w);
            }
        }
    }

    // epilogue: bias + elu, bf16 (hi) out; lo only when requested (head-gemm input)
    // zero-fill K-pad up to LDA=320 (i4 < 80)
#pragma unroll
    for (int k = 0; k < 2; ++k) {
        int i4 = lane + 64 * k;
        if (i4 < 66) {
            float4 a = (k == 0) ? a0 : a1;
            float vals[4] = {a.x, a.y, a.z, a.w};
            ushort hi4[4], lo4[4];
#pragma unroll
            for (int j = 0; j < 4; ++j) {
                float v = vals[j] + bias[i4 * 4 + j];
                v = v > 0.f ? v : (__expf(v) - 1.f);
                split2(v, hi4[j], lo4[j]);
            }
            size_t o = (size_t)node * LDA + i4 * 4;
            *(ushort4*)(outhi + o) = *(ushort4*)hi4;
            if (outlo) *(ushort4*)(outlo + o) = *(ushort4*)lo4;
        } else if (i4 < 80) {
            ushort4 z = {0, 0, 0, 0};
            size_t o = (size_t)node * LDA + i4 * 4;
            *(ushort4*)(outhi + o) = z;
            if (outlo) *(ushort4*)(outlo + o) = z;
        }
    }
}

// ---------------- launch ----------------

extern "C" void kernel_launch(void* const* d_in, const int* in_sizes, int n_in,
                              void* d_out, int out_size, void* d_ws, size_t ws_size,
                              hipStream_t stream) {
    const float* x  = (const float*)d_in[0];
    const int*   ei = (const int*)d_in[1];
    const float* W[4]  = {(const float*)d_in[2],  (const float*)d_in[6],
                          (const float*)d_in[10], (const float*)d_in[14]};
    const float* As[4] = {(const float*)d_in[3],  (const float*)d_in[7],
                          (const float*)d_in[11], (const float*)d_in[15]};
    const float* Ad[4] = {(const float*)d_in[4],  (const float*)d_in[8],
                          (const float*)d_in[12], (const float*)d_in[16]};
    const float* Bb[4] = {(const float*)d_in[5],  (const float*)d_in[9],
                          (const float*)d_in[13], (const float*)d_in[17]};
    const float* Wh = (const float*)d_in[18];
    const float* bh = (const float*)d_in[19];

    // ---- workspace carve ----
    char* p = (char*)d_ws;
    ushort* hBb  = (ushort*)p;          p += (size_t)N_NODES * LDB * 2;      // xh bf16 payload
    ushort* hAhi = (ushort*)p;          p += (size_t)N_NODES * LDA * 2;      // A hi
    ushort* hAlo = (ushort*)p;          p += (size_t)N_NODES * LDA * 2;      // A lo (layer-3 only)
    float* as_  = (float*)p;            p += (size_t)N_NODES * HEADS * 4;
    float* ad_  = (float*)p;            p += (size_t)N_NODES * HEADS * 4;
    const int PK0 = 4, PKH = 10, PKO = 10;   // panels (K/32), padded even
    const int wsz0 = PK0 * NT_HID * 512;
    const int wszH = PKH * NT_HID * 512;
    const int wszO = PKO * NT_HEAD * 512;
    ushort* wfhi[4]; ushort* wflo[4];
    for (int l = 0; l < 4; ++l) {
        int sz = (l == 0) ? wsz0 : wszH;
        wfhi[l] = (ushort*)p; p += (size_t)sz * 2;
        wflo[l] = (ushort*)p; p += (size_t)sz * 2;
    }
    ushort* whhi = (ushort*)p; p += (size_t)wszO * 2;
    ushort* whlo = (ushort*)p; p += (size_t)wszO * 2;
    int* deg  = (int*)p;  p += N_NODES * 4;
    int* cur  = (int*)p;  p += N_NODES * 4;
    int* rowp = (int*)p;  p += (N_NODES + 1) * 4;
    int* csr  = (int*)p;  p += (size_t)TOT_E * 4;

    // ---- CSR build ----
    hipMemsetAsync(deg, 0, sizeof(int) * 2 * N_NODES, stream);  // deg + cur
    int egrid = (TOT_E + 255) / 256;
    deg_k<<<egrid, 256, 0, stream>>>(ei, deg);
    scan_k<<<1, 1024, 0, stream>>>(deg, rowp);
    fill_k<<<egrid, 256, 0, stream>>>(ei, rowp, cur, csr);

    // ---- weight + input conversion ----
    splitx_k<<<(N_NODES * IN_CH + 255) / 256, 256, 0, stream>>>(x, hAhi);
    {
        int tot = PK0 * NT_HID * 64;
        convw_k<<<(tot + 255) / 256, 256, 0, stream>>>(W[0], As[0], Ad[0], IN_CH, DD,
                                                       NT_HID, wfhi[0], wflo[0], tot);
    }
    for (int l = 1; l < 4; ++l) {
        int tot = PKH * NT_HID * 64;
        convw_k<<<(tot + 255) / 256, 256, 0, stream>>>(W[l], As[l], Ad[l], DD, DD,
                                                       NT_HID, wfhi[l], wflo[l], tot);
    }
    {
        int tot = PKO * NT_HEAD * 64;
        convw_k<<<(tot + 255) / 256, 256, 0, stream>>>(Wh, nullptr, nullptr, DD, OUTW,
                                                       NT_HEAD, whhi, whlo, tot);
    }

    dim3 gG((N_NODES + 127) / 128, NT_HID / NTG);   // 157 x 3
    dim3 gO((N_NODES + 127) / 128, NT_HEAD / NTG);  // 157 x 2
    int ggrid = N_NODES / 4;                        // 5000, exact

    for (int l = 0; l < 4; ++l) {
        int kpairs = (l == 0) ? PK0 / 2 : PKH / 2;
        gemm3_k<false><<<gG, 256, 0, stream>>>(hAhi, nullptr, kpairs,
                                               wfhi[l], wflo[l], NT_HID,
                                               hBb, as_, ad_, nullptr, 0, 0, nullptr);
        gat_k<<<ggrid, 256, 0, stream>>>(hBb, as_, ad_, rowp, csr, Bb[l],
                                         hAhi, (l == 3) ? hAlo : nullptr);
    }

    // head readout (3-term for output precision) -> fp32 out [N, 132]
    gemm3_k<true><<<gO, 256, 0, stream>>>(hAhi, hAlo, PKO / 2,
                                          whhi, whlo, NT_HEAD,
                                          nullptr, nullptr, nullptr,
                                          (float*)d_out, OUTW, OUTW, bh);
}

// Round 11
// 504.921 us; speedup vs baseline: 1.2381x; 1.0870x over previous
//
#include <hip/hip_runtime.h>
#include <hip/hip_bf16.h>

#define N_NODES 20000
#define N_EDGES 320000
#define TOT_E   (N_EDGES + N_NODES)   // 340000 with self loops
#define IN_CH   128
#define HEADS   8
#define CH      33
#define DD      264                   // HEADS*CH
#define OUTW    132
#define NEG     0.2f

#define LDB     272                   // bf16 payload row stride
#define LDA     320                   // hA bf16 row stride, K padded to 10*32
#define NT_HID  18                    // 17 payload tiles + 1 stats tile [was|wad]
#define NT_HEAD 12                    // head gemm tiles (132 -> 192, zero-padded)
#define NTG     6                     // compile-time tiles per y-group
#define PK0     4
#define PKH     10
#define PKO     10

typedef unsigned short ushort;
typedef short bf16x8 __attribute__((ext_vector_type(8)));
typedef float f32x4  __attribute__((ext_vector_type(4)));

__device__ inline void split2(float v, ushort& hi, ushort& lo) {
    __hip_bfloat16 h = __float2bfloat16(v);
    float r = v - __bfloat162float(h);
    __hip_bfloat16 l = __float2bfloat16(r);
    hi = *(ushort*)&h;
    lo = *(ushort*)&l;
}

__device__ inline float bf2f(ushort u) {
    union { unsigned int i; float f; } c;
    c.i = ((unsigned int)u) << 16;
    return c.f;
}

// ---------------- CSR build ----------------

__global__ void deg_k(const int* __restrict__ ei, int* __restrict__ deg) {
    int e = blockIdx.x * 256 + threadIdx.x;
    if (e >= TOT_E) return;
    int dst = (e < N_EDGES) ? ei[N_EDGES + e] : (e - N_EDGES);
    atomicAdd(&deg[dst], 1);
}

__global__ __launch_bounds__(1024) void scan_k(const int* __restrict__ deg,
                                               int* __restrict__ rowp) {
    __shared__ int part[1024];
    const int PER = 20;
    int t = threadIdx.x;
    int base = t * PER;
    int s = 0;
    for (int i = 0; i < PER; ++i) {
        int idx = base + i;
        if (idx < N_NODES) s += deg[idx];
    }
    part[t] = s;
    __syncthreads();
    for (int off = 1; off < 1024; off <<= 1) {
        int v = 0;
        if (t >= off) v = part[t - off];
        __syncthreads();
        part[t] += v;
        __syncthreads();
    }
    int run = part[t] - s;
    for (int i = 0; i < PER; ++i) {
        int idx = base + i;
        if (idx < N_NODES) { rowp[idx] = run; run += deg[idx]; }
    }
    if (t == 1023) rowp[N_NODES] = part[1023];
}

__global__ void fill_k(const int* __restrict__ ei, const int* __restrict__ rowp,
                       int* __restrict__ cur, int* __restrict__ csr) {
    int e = blockIdx.x * 256 + threadIdx.x;
    if (e >= TOT_E) return;
    int src, dst;
    if (e < N_EDGES) { src = ei[e]; dst = ei[N_EDGES + e]; }
    else             { src = dst = e - N_EDGES; }
    int p = atomicAdd(&cur[dst], 1);
    csr[rowp[dst] + p] = src;
}

// ---------------- input x -> bf16 (into hAhi, stride LDA) ----------------

__global__ void splitx_k(const float* __restrict__ x, ushort* __restrict__ ahi) {
    int idx = blockIdx.x * 256 + threadIdx.x;
    if (idx >= N_NODES * IN_CH) return;
    int n = idx >> 7, k = idx & 127;
    __hip_bfloat16 h = __float2bfloat16(x[idx]);
    ahi[(size_t)n * LDA + k] = *(ushort*)&h;
}

// ---------------- all weights -> fragment-ordered hi/lo bf16, one launch ----------------
// per segment: Wfrag[((p*NT + t)*64 + kq*16 + m)*8 + j] = V[p*32 + kq*8 + j][t*16 + m]
// last tile (stats, when a_s): col m<8 -> W·a_s head m; m>=8 -> W·a_d head m-8.

__device__ void convw_one(const float* W, const float* a_s, const float* a_d,
                          int K, int NC, int NT, ushort* fhi, ushort* flo, int gid) {
    int p = gid / (NT * 64);
    int rem = gid % (NT * 64);
    int t = rem >> 6, c = rem & 63;
    int kq = c >> 4, m = c & 15;
    int n = t * 16 + m;
    bool stats = (a_s != nullptr) && (t == NT - 1);
    ushort hi8[8], lo8[8];
#pragma unroll
    for (int j = 0; j < 8; ++j) {
        int k = p * 32 + kq * 8 + j;
        float v = 0.f;
        if (k < K) {
            if (stats) {
                const float* av = (m < 8) ? a_s : a_d;
                int h = (m < 8) ? m : m - 8;
                const float* wr = W + (size_t)k * NC + h * CH;
                float s = 0.f;
                for (int cc = 0; cc < CH; ++cc) s += wr[cc] * av[h * CH + cc];
                v = s;
            } else if (n < NC) {
                v = W[(size_t)k * NC + n];
            }
        }
        split2(v, hi8[j], lo8[j]);
    }
    size_t o = ((size_t)gid) * 8;
#pragma unroll
    for (int j = 0; j < 8; ++j) { fhi[o + j] = hi8[j]; flo[o + j] = lo8[j]; }
}

#define SEG0 (PK0 * NT_HID * 64)
#define SEGH (PKH * NT_HID * 64)
#define SEGO (PKO * NT_HEAD * 64)

__global__ void convall_k(
    const float* W0, const float* W1, const float* W2, const float* W3, const float* Wh,
    const float* as0, const float* as1, const float* as2, const float* as3,
    const float* ad0, const float* ad1, const float* ad2, const float* ad3,
    ushort* f0h, ushort* f0l, ushort* f1h, ushort* f1l, ushort* f2h, ushort* f2l,
    ushort* f3h, ushort* f3l, ushort* fhh, ushort* fhl) {
    int gid = blockIdx.x * 256 + threadIdx.x;
    if (gid < SEG0) { convw_one(W0, as0, ad0, IN_CH, DD, NT_HID, f0h, f0l, gid); return; }
    gid -= SEG0;
    if (gid < SEGH) { convw_one(W1, as1, ad1, DD, DD, NT_HID, f1h, f1l, gid); return; }
    gid -= SEGH;
    if (gid < SEGH) { convw_one(W2, as2, ad2, DD, DD, NT_HID, f2h, f2l, gid); return; }
    gid -= SEGH;
    if (gid < SEGH) { convw_one(W3, as3, ad3, DD, DD, NT_HID, f3h, f3l, gid); return; }
    gid -= SEGH;
    if (gid < SEGO) { convw_one(Wh, nullptr, nullptr, DD, OUTW, NT_HEAD, fhh, fhl, gid); }
}

// ---------------- MFMA GEMM, M=128, BK=64, swizzled A LDS ----------------
// Hidden (USE3=0): payload tiles 1-term (Ahi*Whi); stats tile (y==statsY, t==NTG-1)
// gets +Ahi*Wlo. Head (USE3=1): 3-term ahi*bh + ahi*bl + alo*bh, fp32 C + bias.

template<bool USE3>
__global__ __launch_bounds__(256) void gemm4_k(
    const ushort* __restrict__ Ahi, const ushort* __restrict__ Alo, int kpairs,
    const ushort* __restrict__ Bhi, const ushort* __restrict__ Blo, int NTtot, int statsY,
    ushort* __restrict__ Cb16, float* __restrict__ as_, float* __restrict__ ad_,
    float* __restrict__ C, int ldc, int ncguard, const float* __restrict__ bias) {
    extern __shared__ ushort smem[];
    ushort* AlH = smem;                       // [2][8][512] = 8192
    ushort* BlH = smem + 8192;                // [2][NTG][512] = 2*NTG*512
    ushort* EXT = smem + 8192 + 2 * NTG * 512;
    ushort* AlL = EXT;                        // USE3: [2][8][512]
    ushort* BlL = EXT + 8192;                 // USE3: [2][NTG][512]
    ushort* BstL = EXT;                       // !USE3: [2][512] stats-tile lo

    int tid = threadIdx.x;
    int m0 = blockIdx.x * 128;
    int t0 = blockIdx.y * NTG;
    bool sg = ((int)blockIdx.y == statsY);

    f32x4 acc[2][NTG];
#pragma unroll
    for (int mt = 0; mt < 2; ++mt)
#pragma unroll
        for (int t = 0; t < NTG; ++t) acc[mt][t] = (f32x4){0.f, 0.f, 0.f, 0.f};

    int w = tid >> 6, lane = tid & 63;
    int csA = (lane ^ ((lane >> 4) << 1)) * 8;   // swizzled A read offset

    for (int pp = 0; pp < kpairs; ++pp) {
        // stage A: rows of 128 B (2 panels)
        int nA = USE3 ? 2048 : 1024;
        for (int id = tid; id < nA; id += 256) {
            int hl = id >> 10;
            int cid = id & 1023;
            int mrow = cid >> 3, kq8 = cid & 7;
            int panel = kq8 >> 2, kq = kq8 & 3;
            int gm = m0 + mrow;
            uint4 v = {0, 0, 0, 0};
            if (gm < N_NODES) {
                const ushort* src = (hl ? Alo : Ahi) + (size_t)gm * LDA + pp * 64 + kq8 * 8;
                v = *(const uint4*)src;
            }
            int c = kq * 16 + (mrow & 15);
            int cs = c ^ ((c >> 4) << 1);
            ushort* dst = (hl ? AlL : AlH) + panel * 4096 + (mrow >> 4) * 512 + cs * 8;
            *(uint4*)dst = v;
        }
        // stage B hi: 2 panels x NTG x 64 chunks
        for (int id = tid; id < 2 * NTG * 64; id += 256) {
            int c = id & 63;
            int r = id >> 6;
            int t = r % NTG;
            int panel = r / NTG;
            const ushort* src = Bhi + ((size_t)((pp * 2 + panel) * NTtot + t0 + t) * 64 + c) * 8;
            *(uint4*)&BlH[(panel * NTG + t) * 512 + c * 8] = *(const uint4*)src;
        }
        if (USE3) {
            for (int id = tid; id < 2 * NTG * 64; id += 256) {
                int c = id & 63;
                int r = id >> 6;
                int t = r % NTG;
                int panel = r / NTG;
                const ushort* src = Blo + ((size_t)((pp * 2 + panel) * NTtot + t0 + t) * 64 + c) * 8;
                *(uint4*)&BlL[(panel * NTG + t) * 512 + c * 8] = *(const uint4*)src;
            }
        } else if (sg) {
            // stats-tile lo only: 2 panels x 64 chunks (tile t = NTG-1)
            for (int id = tid; id < 2 * 64; id += 256) {
                int c = id & 63;
                int panel = id >> 6;
                const ushort* src = Blo + ((size_t)((pp * 2 + panel) * NTtot + t0 + NTG - 1) * 64 + c) * 8;
                *(uint4*)&BstL[panel * 512 + c * 8] = *(const uint4*)src;
            }
        }
        __syncthreads();

#pragma unroll
        for (int panel = 0; panel < 2; ++panel) {
            bf16x8 a0 = *(const bf16x8*)&AlH[panel * 4096 + (2 * w) * 512 + csA];
            bf16x8 a1 = *(const bf16x8*)&AlH[panel * 4096 + (2 * w + 1) * 512 + csA];
            bf16x8 l0, l1;
            if (USE3) {
                l0 = *(const bf16x8*)&AlL[panel * 4096 + (2 * w) * 512 + csA];
                l1 = *(const bf16x8*)&AlL[panel * 4096 + (2 * w + 1) * 512 + csA];
            }
#pragma unroll
            for (int t = 0; t < NTG; ++t) {
                bf16x8 bh = *(const bf16x8*)&BlH[(panel * NTG + t) * 512 + lane * 8];
                acc[0][t] = __builtin_amdgcn_mfma_f32_16x16x32_bf16(a0, bh, acc[0][t], 0, 0, 0);
                acc[1][t] = __builtin_amdgcn_mfma_f32_16x16x32_bf16(a1, bh, acc[1][t], 0, 0, 0);
                if (USE3) {
                    bf16x8 bl = *(const bf16x8*)&BlL[(panel * NTG + t) * 512 + lane * 8];
                    acc[0][t] = __builtin_amdgcn_mfma_f32_16x16x32_bf16(a0, bl, acc[0][t], 0, 0, 0);
                    acc[1][t] = __builtin_amdgcn_mfma_f32_16x16x32_bf16(a1, bl, acc[1][t], 0, 0, 0);
                    acc[0][t] = __builtin_amdgcn_mfma_f32_16x16x32_bf16(l0, bh, acc[0][t], 0, 0, 0);
                    acc[1][t] = __builtin_amdgcn_mfma_f32_16x16x32_bf16(l1, bh, acc[1][t], 0, 0, 0);
                } else if (t == NTG - 1 && sg) {
                    bf16x8 bst = *(const bf16x8*)&BstL[panel * 512 + lane * 8];
                    acc[0][t] = __builtin_amdgcn_mfma_f32_16x16x32_bf16(a0, bst, acc[0][t], 0, 0, 0);
                    acc[1][t] = __builtin_amdgcn_mfma_f32_16x16x32_bf16(a1, bst, acc[1][t], 0, 0, 0);
                }
            }
        }
        __syncthreads();
    }

    // store: C/D layout col = lane&15, row = (lane>>4)*4 + r
    int col = lane & 15;
#pragma unroll
    for (int mt = 0; mt < 2; ++mt) {
        int rbase = m0 + (2 * w + mt) * 16 + ((lane >> 4) << 2);
#pragma unroll
        for (int t = 0; t < NTG; ++t) {
            int tg = t0 + t;
#pragma unroll
            for (int r = 0; r < 4; ++r) {
                int gm = rbase + r;
                if (gm >= N_NODES) continue;
                float v = acc[mt][t][r];
                if (C) {
                    int gn = tg * 16 + col;
                    if (gn < ncguard) C[(size_t)gm * ldc + gn] = v + bias[gn];
                } else if (tg < 17) {
                    __hip_bfloat16 bv = __float2bfloat16(v);
                    Cb16[(size_t)gm * LDB + tg * 16 + col] = *(ushort*)&bv;
                } else {
                    if (col < 8) as_[(size_t)gm * 8 + col] = v;
                    else         ad_[(size_t)gm * 8 + col - 8] = v;
                }
            }
        }
    }
}

// ---------------- fused softmax + gather-aggregate (unchanged from R10) ----------------

__global__ __launch_bounds__(256) void gat_k(
    const ushort* __restrict__ xb, const float* __restrict__ as_,
    const float* __restrict__ ad_, const int* __restrict__ rowp,
    const int* __restrict__ csr, const float* __restrict__ bias,
    ushort* __restrict__ outhi, ushort* __restrict__ outlo) {
    int wv = threadIdx.x >> 6, lane = threadIdx.x & 63;
    int node = blockIdx.x * 4 + wv;   // grid is exactly N/4
    int r0 = rowp[node], dg = rowp[node + 1] - r0;

    __shared__ float lex[4][64][9];
    __shared__ int   lsrc[4][64];
    __shared__ int   bdg[4];

    if (lane == 0) bdg[wv] = dg;
    __syncthreads();
    int bmax = max(max(bdg[0], bdg[1]), max(bdg[2], bdg[3]));
    int nchunks = (bmax + 63) >> 6;

    float ad[8];
#pragma unroll
    for (int h = 0; h < 8; ++h) ad[h] = ad_[node * 8 + h];

    float mx[8], iv[8], e8[8];
    int myS = node;
    bool fast = (dg <= 64);
    if (fast) {
#pragma unroll
        for (int h = 0; h < 8; ++h) e8[h] = -1e30f;
        if (lane < dg) {
            myS = csr[r0 + lane];
            const float* ap = as_ + (size_t)myS * 8;
#pragma unroll
            for (int h = 0; h < 8; ++h) {
                float e = ap[h] + ad[h];
                e8[h] = e > 0.f ? e : NEG * e;
            }
        }
#pragma unroll
        for (int h = 0; h < 8; ++h) {
            float m = e8[h];
            for (int off = 32; off; off >>= 1) m = fmaxf(m, __shfl_xor(m, off, 64));
            mx[h] = m;
        }
#pragma unroll
        for (int h = 0; h < 8; ++h) {
            float ex = (lane < dg) ? __expf(e8[h] - mx[h]) : 0.f;
            e8[h] = ex;
            float s = ex;
            for (int off = 32; off; off >>= 1) s += __shfl_xor(s, off, 64);
            iv[h] = 1.0f / (s + 1e-16f);
        }
    } else {
#pragma unroll
        for (int h = 0; h < 8; ++h) mx[h] = -1e30f;
        for (int j = lane; j < dg; j += 64) {
            int s = csr[r0 + j];
            const float* ap = as_ + (size_t)s * 8;
#pragma unroll
            for (int h = 0; h < 8; ++h) {
                float e = ap[h] + ad[h];
                e = e > 0.f ? e : NEG * e;
                mx[h] = fmaxf(mx[h], e);
            }
        }
#pragma unroll
        for (int h = 0; h < 8; ++h)
            for (int off = 32; off; off >>= 1)
                mx[h] = fmaxf(mx[h], __shfl_xor(mx[h], off, 64));
        float sm[8] = {0.f, 0.f, 0.f, 0.f, 0.f, 0.f, 0.f, 0.f};
        for (int j = lane; j < dg; j += 64) {
            int s = csr[r0 + j];
            const float* ap = as_ + (size_t)s * 8;
#pragma unroll
            for (int h = 0; h < 8; ++h) {
                float e = ap[h] + ad[h];
                e = e > 0.f ? e : NEG * e;
                sm[h] += __expf(e - mx[h]);
            }
        }
#pragma unroll
        for (int h = 0; h < 8; ++h) {
            for (int off = 32; off; off >>= 1) sm[h] += __shfl_xor(sm[h], off, 64);
            iv[h] = 1.0f / (sm[h] + 1e-16f);
        }
    }

    int h0[4], h1[4];
#pragma unroll
    for (int j = 0; j < 4; ++j) {
        h0[j] = (4 * lane + j) / 33;
        h1[j] = (4 * (lane + 64) + j) / 33;
    }
    float4 a0 = {0.f, 0.f, 0.f, 0.f}, a1 = {0.f, 0.f, 0.f, 0.f};

    for (int c = 0; c < nchunks; ++c) {
        int base = c << 6, j = base + lane;
        __syncthreads();
        int s = node;
        float al[8];
#pragma unroll
        for (int h = 0; h < 8; ++h) al[h] = 0.f;
        if (j < dg) {
            if (fast) {
                s = myS;
#pragma unroll
                for (int h = 0; h < 8; ++h) al[h] = e8[h] * iv[h];
            } else {
                s = csr[r0 + j];
                const float* ap = as_ + (size_t)s * 8;
#pragma unroll
                for (int h = 0; h < 8; ++h) {
                    float e = ap[h] + ad[h];
                    e = e > 0.f ? e : NEG * e;
                    al[h] = __expf(e - mx[h]) * iv[h];
                }
            }
        }
        lsrc[wv][lane] = s;
#pragma unroll
        for (int h = 0; h < 8; ++h) lex[wv][lane][h] = al[h];
        __syncthreads();

        int rem = dg - base;
        int cnt = rem > 64 ? 64 : (rem < 0 ? 0 : rem);
        int cnt4 = (cnt + 3) & ~3;
        for (int jj = 0; jj < cnt4; jj += 4) {
            int s0 = lsrc[wv][jj + 0], s1 = lsrc[wv][jj + 1];
            int s2 = lsrc[wv][jj + 2], s3 = lsrc[wv][jj + 3];
            const ushort4* p0 = (const ushort4*)(xb + (size_t)s0 * LDB);
            const ushort4* p1 = (const ushort4*)(xb + (size_t)s1 * LDB);
            const ushort4* p2 = (const ushort4*)(xb + (size_t)s2 * LDB);
            const ushort4* p3 = (const ushort4*)(xb + (size_t)s3 * LDB);
            ushort4 v0 = p0[lane], v1 = p1[lane], v2 = p2[lane], v3 = p3[lane];
            ushort4 w0, w1, w2, w3;
            if (lane < 2) { w0 = p0[64 + lane]; w1 = p1[64 + lane]; w2 = p2[64 + lane]; w3 = p3[64 + lane]; }
            const float* x0 = lex[wv][jj + 0];
            const float* x1 = lex[wv][jj + 1];
            const float* x2 = lex[wv][jj + 2];
            const float* x3 = lex[wv][jj + 3];
            a0.x += x0[h0[0]] * bf2f(v0.x) + x1[h0[0]] * bf2f(v1.x)
                  + x2[h0[0]] * bf2f(v2.x) + x3[h0[0]] * bf2f(v3.x);
            a0.y += x0[h0[1]] * bf2f(v0.y) + x1[h0[1]] * bf2f(v1.y)
                  + x2[h0[1]] * bf2f(v2.y) + x3[h0[1]] * bf2f(v3.y);
            a0.z += x0[h0[2]] * bf2f(v0.z) + x1[h0[2]] * bf2f(v1.z)
                  + x2[h0[2]] * bf2f(v2.z) + x3[h0[2]] * bf2f(v3.z);
            a0.w += x0[h0[3]] * bf2f(v0.w) + x1[h0[3]] * bf2f(v1.w)
                  + x2[h0[3]] * bf2f(v2.w) + x3[h0[3]] * bf2f(v3.w);
            if (lane < 2) {
                a1.x += x0[h1[0]] * bf2f(w0.x) + x1[h1[0]] * bf2f(w1.x)
                      + x2[h1[0]] * bf2f(w2.x) + x3[h1[0]] * bf2f(w3.x);
                a1.y += x0[h1[1]] * bf2f(w0.y) + x1[h1[1]] * bf2f(w1.y)
                      + x2[h1[1]] * bf2f(w2.y) + x3[h1[1]] * bf2f(w3.y);
                a1.z += x0[h1[2]] * bf2f(w0.z) + x1[h1[2]] * bf2f(w1.z)
                      + x2[h1[2]] * bf2f(w2.z) + x3[h1[2]] * bf2f(w3.z);
                a1.w += x0[h1[3]] * bf2f(w0.w) + x1[h1[3]] * bf2f(w1.w)
                      + x2[h1[3]] * bf2f(w2.w) + x3[h1[3]] * bf2f(w3.w);
            }
        }
    }

    // epilogue: bias + elu, bf16 (hi) out; lo only when requested; zero K-pad to LDA
#pragma unroll
    for (int k = 0; k < 2; ++k) {
        int i4 = lane + 64 * k;
        if (i4 < 66) {
            float4 a = (k == 0) ? a0 : a1;
            float vals[4] = {a.x, a.y, a.z, a.w};
            ushort hi4[4], lo4[4];
#pragma unroll
            for (int j = 0; j < 4; ++j) {
                float v = vals[j] + bias[i4 * 4 + j];
                v = v > 0.f ? v : (__expf(v) - 1.f);
                split2(v, hi4[j], lo4[j]);
            }
            size_t o = (size_t)node * LDA + i4 * 4;
            *(ushort4*)(outhi + o) = *(ushort4*)hi4;
            if (outlo) *(ushort4*)(outlo + o) = *(ushort4*)lo4;
        } else if (i4 < 80) {
            ushort4 z = {0, 0, 0, 0};
            size_t o = (size_t)node * LDA + i4 * 4;
            *(ushort4*)(outhi + o) = z;
            if (outlo) *(ushort4*)(outlo + o) = z;
        }
    }
}

// ---------------- launch ----------------

extern "C" void kernel_launch(void* const* d_in, const int* in_sizes, int n_in,
                              void* d_out, int out_size, void* d_ws, size_t ws_size,
                              hipStream_t stream) {
    const float* x  = (const float*)d_in[0];
    const int*   ei = (const int*)d_in[1];
    const float* W[4]  = {(const float*)d_in[2],  (const float*)d_in[6],
                          (const float*)d_in[10], (const float*)d_in[14]};
    const float* As[4] = {(const float*)d_in[3],  (const float*)d_in[7],
                          (const float*)d_in[11], (const float*)d_in[15]};
    const float* Ad[4] = {(const float*)d_in[4],  (const float*)d_in[8],
                          (const float*)d_in[12], (const float*)d_in[16]};
    const float* Bb[4] = {(const float*)d_in[5],  (const float*)d_in[9],
                          (const float*)d_in[13], (const float*)d_in[17]};
    const float* Wh = (const float*)d_in[18];
    const float* bh = (const float*)d_in[19];

    // ---- workspace carve ----
    char* p = (char*)d_ws;
    ushort* hBb  = (ushort*)p;          p += (size_t)N_NODES * LDB * 2;
    ushort* hAhi = (ushort*)p;          p += (size_t)N_NODES * LDA * 2;
    ushort* hAlo = (ushort*)p;          p += (size_t)N_NODES * LDA * 2;
    float* as_  = (float*)p;            p += (size_t)N_NODES * HEADS * 4;
    float* ad_  = (float*)p;            p += (size_t)N_NODES * HEADS * 4;
    const int wsz0 = PK0 * NT_HID * 512;
    const int wszH = PKH * NT_HID * 512;
    const int wszO = PKO * NT_HEAD * 512;
    ushort* wfhi[4]; ushort* wflo[4];
    for (int l = 0; l < 4; ++l) {
        int sz = (l == 0) ? wsz0 : wszH;
        wfhi[l] = (ushort*)p; p += (size_t)sz * 2;
        wflo[l] = (ushort*)p; p += (size_t)sz * 2;
    }
    ushort* whhi = (ushort*)p; p += (size_t)wszO * 2;
    ushort* whlo = (ushort*)p; p += (size_t)wszO * 2;
    int* deg  = (int*)p;  p += N_NODES * 4;
    int* cur  = (int*)p;  p += N_NODES * 4;
    int* rowp = (int*)p;  p += (N_NODES + 1) * 4;
    int* csr  = (int*)p;  p += (size_t)TOT_E * 4;

    // ---- CSR build ----
    hipMemsetAsync(deg, 0, sizeof(int) * 2 * N_NODES, stream);  // deg + cur
    int egrid = (TOT_E + 255) / 256;
    deg_k<<<egrid, 256, 0, stream>>>(ei, deg);
    scan_k<<<1, 1024, 0, stream>>>(deg, rowp);
    fill_k<<<egrid, 256, 0, stream>>>(ei, rowp, cur, csr);

    // ---- weight + input conversion (single launch for all weights) ----
    splitx_k<<<(N_NODES * IN_CH + 255) / 256, 256, 0, stream>>>(x, hAhi);
    {
        int tot = SEG0 + 3 * SEGH + SEGO;
        convall_k<<<(tot + 255) / 256, 256, 0, stream>>>(
            W[0], W[1], W[2], W[3], Wh,
            As[0], As[1], As[2], As[3],
            Ad[0], Ad[1], Ad[2], Ad[3],
            wfhi[0], wflo[0], wfhi[1], wflo[1], wfhi[2], wflo[2],
            wfhi[3], wflo[3], whhi, whlo);
    }

    dim3 gG((N_NODES + 127) / 128, NT_HID / NTG);   // 157 x 3
    dim3 gO((N_NODES + 127) / 128, NT_HEAD / NTG);  // 157 x 2
    size_t smHid = (size_t)(8192 + 2 * NTG * 512 + 2 * 512) * 2;             // ~30.7 KB
    size_t smHead = (size_t)(8192 + 2 * NTG * 512 + 8192 + 2 * NTG * 512) * 2; // ~57.3 KB
    int ggrid = N_NODES / 4;

    for (int l = 0; l < 4; ++l) {
        int kpairs = (l == 0) ? PK0 / 2 : PKH / 2;
        gemm4_k<false><<<gG, 256, smHid, stream>>>(hAhi, nullptr, kpairs,
                                                   wfhi[l], wflo[l], NT_HID, 2,
                                                   hBb, as_, ad_, nullptr, 0, 0, nullptr);
        gat_k<<<ggrid, 256, 0, stream>>>(hBb, as_, ad_, rowp, csr, Bb[l],
                                         hAhi, (l == 3) ? hAlo : nullptr);
    }

    // head readout (3-term) -> fp32 out [N, 132]
    gemm4_k<true><<<gO, 256, smHead, stream>>>(hAhi, hAlo, PKO / 2,
                                               whhi, whlo, NT_HEAD, -1,
                                               nullptr, nullptr, nullptr,
                                               (float*)d_out, OUTW, OUTW, bh);
}

// Round 12
// 497.683 us; speedup vs baseline: 1.2561x; 1.0145x over previous
//
#include <hip/hip_runtime.h>
#include <hip/hip_bf16.h>

#define N_NODES 20000
#define N_EDGES 320000
#define TOT_E   (N_EDGES + N_NODES)   // 340000 with self loops
#define IN_CH   128
#define HEADS   8
#define CH      33
#define DD      264                   // HEADS*CH
#define OUTW    132
#define NEG     0.2f

#define LDB     272                   // bf16 payload row stride
#define LDA     320                   // hA bf16 row stride, K padded to 10*32
#define NT_HID  18                    // 17 payload tiles + 1 stats tile [was|wad]
#define NT_HEAD 12                    // head gemm tiles (132 -> 192, zero-padded)
#define NTG     6                     // compile-time tiles per y-group
#define PK0     4
#define PKH     10
#define PKO     10

typedef unsigned short ushort;
typedef short bf16x8 __attribute__((ext_vector_type(8)));
typedef float f32x4  __attribute__((ext_vector_type(4)));

__device__ inline void split2(float v, ushort& hi, ushort& lo) {
    __hip_bfloat16 h = __float2bfloat16(v);
    float r = v - __bfloat162float(h);
    __hip_bfloat16 l = __float2bfloat16(r);
    hi = *(ushort*)&h;
    lo = *(ushort*)&l;
}

__device__ inline float bf2f(ushort u) {
    union { unsigned int i; float f; } c;
    c.i = ((unsigned int)u) << 16;
    return c.f;
}

// ---------------- CSR build ----------------

__global__ void deg_k(const int* __restrict__ ei, int* __restrict__ deg) {
    int e = blockIdx.x * 256 + threadIdx.x;
    if (e >= TOT_E) return;
    int dst = (e < N_EDGES) ? ei[N_EDGES + e] : (e - N_EDGES);
    atomicAdd(&deg[dst], 1);
}

__global__ __launch_bounds__(1024) void scan_k(const int* __restrict__ deg,
                                               int* __restrict__ rowp) {
    __shared__ int part[1024];
    const int PER = 20;
    int t = threadIdx.x;
    int base = t * PER;
    int s = 0;
    for (int i = 0; i < PER; ++i) {
        int idx = base + i;
        if (idx < N_NODES) s += deg[idx];
    }
    part[t] = s;
    __syncthreads();
    for (int off = 1; off < 1024; off <<= 1) {
        int v = 0;
        if (t >= off) v = part[t - off];
        __syncthreads();
        part[t] += v;
        __syncthreads();
    }
    int run = part[t] - s;
    for (int i = 0; i < PER; ++i) {
        int idx = base + i;
        if (idx < N_NODES) { rowp[idx] = run; run += deg[idx]; }
    }
    if (t == 1023) rowp[N_NODES] = part[1023];
}

__global__ void fill_k(const int* __restrict__ ei, const int* __restrict__ rowp,
                       int* __restrict__ cur, int* __restrict__ csr) {
    int e = blockIdx.x * 256 + threadIdx.x;
    if (e >= TOT_E) return;
    int src, dst;
    if (e < N_EDGES) { src = ei[e]; dst = ei[N_EDGES + e]; }
    else             { src = dst = e - N_EDGES; }
    int p = atomicAdd(&cur[dst], 1);
    csr[rowp[dst] + p] = src;
}

// ---------------- input x -> bf16 (into hAhi, stride LDA) ----------------

__global__ void splitx_k(const float* __restrict__ x, ushort* __restrict__ ahi) {
    int idx = blockIdx.x * 256 + threadIdx.x;
    if (idx >= N_NODES * IN_CH) return;
    int n = idx >> 7, k = idx & 127;
    __hip_bfloat16 h = __float2bfloat16(x[idx]);
    ahi[(size_t)n * LDA + k] = *(ushort*)&h;
}

// ---------------- all weights -> fragment-ordered hi/lo bf16, one launch ----------------

__device__ void convw_one(const float* W, const float* a_s, const float* a_d,
                          int K, int NC, int NT, ushort* fhi, ushort* flo, int gid) {
    int p = gid / (NT * 64);
    int rem = gid % (NT * 64);
    int t = rem >> 6, c = rem & 63;
    int kq = c >> 4, m = c & 15;
    int n = t * 16 + m;
    bool stats = (a_s != nullptr) && (t == NT - 1);
    ushort hi8[8], lo8[8];
#pragma unroll
    for (int j = 0; j < 8; ++j) {
        int k = p * 32 + kq * 8 + j;
        float v = 0.f;
        if (k < K) {
            if (stats) {
                const float* av = (m < 8) ? a_s : a_d;
                int h = (m < 8) ? m : m - 8;
                const float* wr = W + (size_t)k * NC + h * CH;
                float s = 0.f;
                for (int cc = 0; cc < CH; ++cc) s += wr[cc] * av[h * CH + cc];
                v = s;
            } else if (n < NC) {
                v = W[(size_t)k * NC + n];
            }
        }
        split2(v, hi8[j], lo8[j]);
    }
    size_t o = ((size_t)gid) * 8;
#pragma unroll
    for (int j = 0; j < 8; ++j) { fhi[o + j] = hi8[j]; flo[o + j] = lo8[j]; }
}

#define SEG0 (PK0 * NT_HID * 64)
#define SEGH (PKH * NT_HID * 64)
#define SEGO (PKO * NT_HEAD * 64)

__global__ void convall_k(
    const float* W0, const float* W1, const float* W2, const float* W3, const float* Wh,
    const float* as0, const float* as1, const float* as2, const float* as3,
    const float* ad0, const float* ad1, const float* ad2, const float* ad3,
    ushort* f0h, ushort* f0l, ushort* f1h, ushort* f1l, ushort* f2h, ushort* f2l,
    ushort* f3h, ushort* f3l, ushort* fhh, ushort* fhl) {
    int gid = blockIdx.x * 256 + threadIdx.x;
    if (gid < SEG0) { convw_one(W0, as0, ad0, IN_CH, DD, NT_HID, f0h, f0l, gid); return; }
    gid -= SEG0;
    if (gid < SEGH) { convw_one(W1, as1, ad1, DD, DD, NT_HID, f1h, f1l, gid); return; }
    gid -= SEGH;
    if (gid < SEGH) { convw_one(W2, as2, ad2, DD, DD, NT_HID, f2h, f2l, gid); return; }
    gid -= SEGH;
    if (gid < SEGH) { convw_one(W3, as3, ad3, DD, DD, NT_HID, f3h, f3l, gid); return; }
    gid -= SEGH;
    if (gid < SEGO) { convw_one(Wh, nullptr, nullptr, DD, OUTW, NT_HEAD, fhh, fhl, gid); }
}

// ---------------- MFMA GEMM, M=128, BK=64, swizzled A LDS (unchanged from R11) --------

template<bool USE3>
__global__ __launch_bounds__(256) void gemm4_k(
    const ushort* __restrict__ Ahi, const ushort* __restrict__ Alo, int kpairs,
    const ushort* __restrict__ Bhi, const ushort* __restrict__ Blo, int NTtot, int statsY,
    ushort* __restrict__ Cb16, float* __restrict__ as_, float* __restrict__ ad_,
    float* __restrict__ C, int ldc, int ncguard, const float* __restrict__ bias) {
    extern __shared__ ushort smem[];
    ushort* AlH = smem;                       // [2][8][512] = 8192
    ushort* BlH = smem + 8192;                // [2][NTG][512]
    ushort* EXT = smem + 8192 + 2 * NTG * 512;
    ushort* AlL = EXT;                        // USE3
    ushort* BlL = EXT + 8192;                 // USE3
    ushort* BstL = EXT;                       // !USE3: stats-tile lo

    int tid = threadIdx.x;
    int m0 = blockIdx.x * 128;
    int t0 = blockIdx.y * NTG;
    bool sg = ((int)blockIdx.y == statsY);

    f32x4 acc[2][NTG];
#pragma unroll
    for (int mt = 0; mt < 2; ++mt)
#pragma unroll
        for (int t = 0; t < NTG; ++t) acc[mt][t] = (f32x4){0.f, 0.f, 0.f, 0.f};

    int w = tid >> 6, lane = tid & 63;
    int csA = (lane ^ ((lane >> 4) << 1)) * 8;

    for (int pp = 0; pp < kpairs; ++pp) {
        int nA = USE3 ? 2048 : 1024;
        for (int id = tid; id < nA; id += 256) {
            int hl = id >> 10;
            int cid = id & 1023;
            int mrow = cid >> 3, kq8 = cid & 7;
            int panel = kq8 >> 2, kq = kq8 & 3;
            int gm = m0 + mrow;
            uint4 v = {0, 0, 0, 0};
            if (gm < N_NODES) {
                const ushort* src = (hl ? Alo : Ahi) + (size_t)gm * LDA + pp * 64 + kq8 * 8;
                v = *(const uint4*)src;
            }
            int c = kq * 16 + (mrow & 15);
            int cs = c ^ ((c >> 4) << 1);
            ushort* dst = (hl ? AlL : AlH) + panel * 4096 + (mrow >> 4) * 512 + cs * 8;
            *(uint4*)dst = v;
        }
        for (int id = tid; id < 2 * NTG * 64; id += 256) {
            int c = id & 63;
            int r = id >> 6;
            int t = r % NTG;
            int panel = r / NTG;
            const ushort* src = Bhi + ((size_t)((pp * 2 + panel) * NTtot + t0 + t) * 64 + c) * 8;
            *(uint4*)&BlH[(panel * NTG + t) * 512 + c * 8] = *(const uint4*)src;
        }
        if (USE3) {
            for (int id = tid; id < 2 * NTG * 64; id += 256) {
                int c = id & 63;
                int r = id >> 6;
                int t = r % NTG;
                int panel = r / NTG;
                const ushort* src = Blo + ((size_t)((pp * 2 + panel) * NTtot + t0 + t) * 64 + c) * 8;
                *(uint4*)&BlL[(panel * NTG + t) * 512 + c * 8] = *(const uint4*)src;
            }
        } else if (sg) {
            for (int id = tid; id < 2 * 64; id += 256) {
                int c = id & 63;
                int panel = id >> 6;
                const ushort* src = Blo + ((size_t)((pp * 2 + panel) * NTtot + t0 + NTG - 1) * 64 + c) * 8;
                *(uint4*)&BstL[panel * 512 + c * 8] = *(const uint4*)src;
            }
        }
        __syncthreads();

#pragma unroll
        for (int panel = 0; panel < 2; ++panel) {
            bf16x8 a0 = *(const bf16x8*)&AlH[panel * 4096 + (2 * w) * 512 + csA];
            bf16x8 a1 = *(const bf16x8*)&AlH[panel * 4096 + (2 * w + 1) * 512 + csA];
            bf16x8 l0, l1;
            if (USE3) {
                l0 = *(const bf16x8*)&AlL[panel * 4096 + (2 * w) * 512 + csA];
                l1 = *(const bf16x8*)&AlL[panel * 4096 + (2 * w + 1) * 512 + csA];
            }
#pragma unroll
            for (int t = 0; t < NTG; ++t) {
                bf16x8 bh = *(const bf16x8*)&BlH[(panel * NTG + t) * 512 + lane * 8];
                acc[0][t] = __builtin_amdgcn_mfma_f32_16x16x32_bf16(a0, bh, acc[0][t], 0, 0, 0);
                acc[1][t] = __builtin_amdgcn_mfma_f32_16x16x32_bf16(a1, bh, acc[1][t], 0, 0, 0);
                if (USE3) {
                    bf16x8 bl = *(const bf16x8*)&BlL[(panel * NTG + t) * 512 + lane * 8];
                    acc[0][t] = __builtin_amdgcn_mfma_f32_16x16x32_bf16(a0, bl, acc[0][t], 0, 0, 0);
                    acc[1][t] = __builtin_amdgcn_mfma_f32_16x16x32_bf16(a1, bl, acc[1][t], 0, 0, 0);
                    acc[0][t] = __builtin_amdgcn_mfma_f32_16x16x32_bf16(l0, bh, acc[0][t], 0, 0, 0);
                    acc[1][t] = __builtin_amdgcn_mfma_f32_16x16x32_bf16(l1, bh, acc[1][t], 0, 0, 0);
                } else if (t == NTG - 1 && sg) {
                    bf16x8 bst = *(const bf16x8*)&BstL[panel * 512 + lane * 8];
                    acc[0][t] = __builtin_amdgcn_mfma_f32_16x16x32_bf16(a0, bst, acc[0][t], 0, 0, 0);
                    acc[1][t] = __builtin_amdgcn_mfma_f32_16x16x32_bf16(a1, bst, acc[1][t], 0, 0, 0);
                }
            }
        }
        __syncthreads();
    }

    int col = lane & 15;
#pragma unroll
    for (int mt = 0; mt < 2; ++mt) {
        int rbase = m0 + (2 * w + mt) * 16 + ((lane >> 4) << 2);
#pragma unroll
        for (int t = 0; t < NTG; ++t) {
            int tg = t0 + t;
#pragma unroll
            for (int r = 0; r < 4; ++r) {
                int gm = rbase + r;
                if (gm >= N_NODES) continue;
                float v = acc[mt][t][r];
                if (C) {
                    int gn = tg * 16 + col;
                    if (gn < ncguard) C[(size_t)gm * ldc + gn] = v + bias[gn];
                } else if (tg < 17) {
                    __hip_bfloat16 bv = __float2bfloat16(v);
                    Cb16[(size_t)gm * LDB + tg * 16 + col] = *(ushort*)&bv;
                } else {
                    if (col < 8) as_[(size_t)gm * 8 + col] = v;
                    else         ad_[(size_t)gm * 8 + col - 8] = v;
                }
            }
        }
    }
}

// ---------------- fused softmax + gather-aggregate: barrier-free wave-sync ----------------
// 4 waves/block = 4 nodes. lex/lsrc are PER-WAVE regions: same-wave LDS write->read
// is program-ordered on CDNA (lgkmcnt), so no __syncthreads needed -- each wave runs
// its own dg independently (no bmax coupling).

__global__ __launch_bounds__(256) void gat_k(
    const ushort* __restrict__ xb, const float* __restrict__ as_,
    const float* __restrict__ ad_, const int* __restrict__ rowp,
    const int* __restrict__ csr, const float* __restrict__ bias,
    ushort* __restrict__ outhi, ushort* __restrict__ outlo) {
    int wv = threadIdx.x >> 6, lane = threadIdx.x & 63;
    int node = blockIdx.x * 4 + wv;   // grid is exactly N/4
    int r0 = rowp[node], dg = rowp[node + 1] - r0;

    __shared__ float lex[4][64][9];
    __shared__ int   lsrc[4][64];

    float ad[8];
#pragma unroll
    for (int h = 0; h < 8; ++h) ad[h] = ad_[node * 8 + h];

    float mx[8], iv[8], e8[8];
    int myS = node;
    bool fast = (dg <= 64);
    if (fast) {
#pragma unroll
        for (int h = 0; h < 8; ++h) e8[h] = -1e30f;
        if (lane < dg) {
            myS = csr[r0 + lane];
            const float* ap = as_ + (size_t)myS * 8;
#pragma unroll
            for (int h = 0; h < 8; ++h) {
                float e = ap[h] + ad[h];
                e8[h] = e > 0.f ? e : NEG * e;
            }
        }
#pragma unroll
        for (int h = 0; h < 8; ++h) {
            float m = e8[h];
            for (int off = 32; off; off >>= 1) m = fmaxf(m, __shfl_xor(m, off, 64));
            mx[h] = m;
        }
#pragma unroll
        for (int h = 0; h < 8; ++h) {
            float ex = (lane < dg) ? __expf(e8[h] - mx[h]) : 0.f;
            e8[h] = ex;
            float s = ex;
            for (int off = 32; off; off >>= 1) s += __shfl_xor(s, off, 64);
            iv[h] = 1.0f / (s + 1e-16f);
        }
    } else {
#pragma unroll
        for (int h = 0; h < 8; ++h) mx[h] = -1e30f;
        for (int j = lane; j < dg; j += 64) {
            int s = csr[r0 + j];
            const float* ap = as_ + (size_t)s * 8;
#pragma unroll
            for (int h = 0; h < 8; ++h) {
                float e = ap[h] + ad[h];
                e = e > 0.f ? e : NEG * e;
                mx[h] = fmaxf(mx[h], e);
            }
        }
#pragma unroll
        for (int h = 0; h < 8; ++h)
            for (int off = 32; off; off >>= 1)
                mx[h] = fmaxf(mx[h], __shfl_xor(mx[h], off, 64));
        float sm[8] = {0.f, 0.f, 0.f, 0.f, 0.f, 0.f, 0.f, 0.f};
        for (int j = lane; j < dg; j += 64) {
            int s = csr[r0 + j];
            const float* ap = as_ + (size_t)s * 8;
#pragma unroll
            for (int h = 0; h < 8; ++h) {
                float e = ap[h] + ad[h];
                e = e > 0.f ? e : NEG * e;
                sm[h] += __expf(e - mx[h]);
            }
        }
#pragma unroll
        for (int h = 0; h < 8; ++h) {
            for (int off = 32; off; off >>= 1) sm[h] += __shfl_xor(sm[h], off, 64);
            iv[h] = 1.0f / (sm[h] + 1e-16f);
        }
    }

    int h0[4], h1[4];
#pragma unroll
    for (int j = 0; j < 4; ++j) {
        h0[j] = (4 * lane + j) / 33;
        h1[j] = (4 * (lane + 64) + j) / 33;
    }
    float4 a0 = {0.f, 0.f, 0.f, 0.f}, a1 = {0.f, 0.f, 0.f, 0.f};

    int nchunks = (dg + 63) >> 6;   // own degree only -- no cross-wave coupling
    for (int c = 0; c < nchunks; ++c) {
        int base = c << 6, j = base + lane;
        int s = node;
        float al[8];
#pragma unroll
        for (int h = 0; h < 8; ++h) al[h] = 0.f;
        if (j < dg) {
            if (fast) {
                s = myS;
#pragma unroll
                for (int h = 0; h < 8; ++h) al[h] = e8[h] * iv[h];
            } else {
                s = csr[r0 + j];
                const float* ap = as_ + (size_t)s * 8;
#pragma unroll
                for (int h = 0; h < 8; ++h) {
                    float e = ap[h] + ad[h];
                    e = e > 0.f ? e : NEG * e;
                    al[h] = __expf(e - mx[h]) * iv[h];
                }
            }
        }
        lsrc[wv][lane] = s;
#pragma unroll
        for (int h = 0; h < 8; ++h) lex[wv][lane][h] = al[h];
        __builtin_amdgcn_wave_barrier();   // scheduling fence: no reorder across staging

        int rem = dg - base;
        int cnt = rem > 64 ? 64 : rem;
        int cnt4 = (cnt + 3) & ~3;
        for (int jj = 0; jj < cnt4; jj += 4) {
            int s0 = lsrc[wv][jj + 0], s1 = lsrc[wv][jj + 1];
            int s2 = lsrc[wv][jj + 2], s3 = lsrc[wv][jj + 3];
            const ushort4* p0 = (const ushort4*)(xb + (size_t)s0 * LDB);
            const ushort4* p1 = (const ushort4*)(xb + (size_t)s1 * LDB);
            const ushort4* p2 = (const ushort4*)(xb + (size_t)s2 * LDB);
            const ushort4* p3 = (const ushort4*)(xb + (size_t)s3 * LDB);
            ushort4 v0 = p0[lane], v1 = p1[lane], v2 = p2[lane], v3 = p3[lane];
            ushort4 w0, w1, w2, w3;
            if (lane < 2) { w0 = p0[64 + lane]; w1 = p1[64 + lane]; w2 = p2[64 + lane]; w3 = p3[64 + lane]; }
            const float* x0 = lex[wv][jj + 0];
            const float* x1 = lex[wv][jj + 1];
            const float* x2 = lex[wv][jj + 2];
            const float* x3 = lex[wv][jj + 3];
            a0.x += x0[h0[0]] * bf2f(v0.x) + x1[h0[0]] * bf2f(v1.x)
                  + x2[h0[0]] * bf2f(v2.x) + x3[h0[0]] * bf2f(v3.x);
            a0.y += x0[h0[1]] * bf2f(v0.y) + x1[h0[1]] * bf2f(v1.y)
                  + x2[h0[1]] * bf2f(v2.y) + x3[h0[1]] * bf2f(v3.y);
            a0.z += x0[h0[2]] * bf2f(v0.z) + x1[h0[2]] * bf2f(v1.z)
                  + x2[h0[2]] * bf2f(v2.z) + x3[h0[2]] * bf2f(v3.z);
            a0.w += x0[h0[3]] * bf2f(v0.w) + x1[h0[3]] * bf2f(v1.w)
                  + x2[h0[3]] * bf2f(v2.w) + x3[h0[3]] * bf2f(v3.w);
            if (lane < 2) {
                a1.x += x0[h1[0]] * bf2f(w0.x) + x1[h1[0]] * bf2f(w1.x)
                      + x2[h1[0]] * bf2f(w2.x) + x3[h1[0]] * bf2f(w3.x);
                a1.y += x0[h1[1]] * bf2f(w0.y) + x1[h1[1]] * bf2f(w1.y)
                      + x2[h1[1]] * bf2f(w2.y) + x3[h1[1]] * bf2f(w3.y);
                a1.z += x0[h1[2]] * bf2f(w0.z) + x1[h1[2]] * bf2f(w1.z)
                      + x2[h1[2]] * bf2f(w2.z) + x3[h1[2]] * bf2f(w3.z);
                a1.w += x0[h1[3]] * bf2f(w0.w) + x1[h1[3]] * bf2f(w1.w)
                      + x2[h1[3]] * bf2f(w2.w) + x3[h1[3]] * bf2f(w3.w);
            }
        }
        __builtin_amdgcn_wave_barrier();   // fence before next chunk's staging writes
    }

    // epilogue: bias + elu, bf16 (hi) out; lo only when requested; zero K-pad to LDA
#pragma unroll
    for (int k = 0; k < 2; ++k) {
        int i4 = lane + 64 * k;
        if (i4 < 66) {
            float4 a = (k == 0) ? a0 : a1;
            float vals[4] = {a.x, a.y, a.z, a.w};
            ushort hi4[4], lo4[4];
#pragma unroll
            for (int j = 0; j < 4; ++j) {
                float v = vals[j] + bias[i4 * 4 + j];
                v = v > 0.f ? v : (__expf(v) - 1.f);
                split2(v, hi4[j], lo4[j]);
            }
            size_t o = (size_t)node * LDA + i4 * 4;
            *(ushort4*)(outhi + o) = *(ushort4*)hi4;
            if (outlo) *(ushort4*)(outlo + o) = *(ushort4*)lo4;
        } else if (i4 < 80) {
            ushort4 z = {0, 0, 0, 0};
            size_t o = (size_t)node * LDA + i4 * 4;
            *(ushort4*)(outhi + o) = z;
            if (outlo) *(ushort4*)(outlo + o) = z;
        }
    }
}

// ---------------- launch ----------------

extern "C" void kernel_launch(void* const* d_in, const int* in_sizes, int n_in,
                              void* d_out, int out_size, void* d_ws, size_t ws_size,
                              hipStream_t stream) {
    const float* x  = (const float*)d_in[0];
    const int*   ei = (const int*)d_in[1];
    const float* W[4]  = {(const float*)d_in[2],  (const float*)d_in[6],
                          (const float*)d_in[10], (const float*)d_in[14]};
    const float* As[4] = {(const float*)d_in[3],  (const float*)d_in[7],
                          (const float*)d_in[11], (const float*)d_in[15]};
    const float* Ad[4] = {(const float*)d_in[4],  (const float*)d_in[8],
                          (const float*)d_in[12], (const float*)d_in[16]};
    const float* Bb[4] = {(const float*)d_in[5],  (const float*)d_in[9],
                          (const float*)d_in[13], (const float*)d_in[17]};
    const float* Wh = (const float*)d_in[18];
    const float* bh = (const float*)d_in[19];

    // ---- workspace carve ----
    char* p = (char*)d_ws;
    ushort* hBb  = (ushort*)p;          p += (size_t)N_NODES * LDB * 2;
    ushort* hAhi = (ushort*)p;          p += (size_t)N_NODES * LDA * 2;
    ushort* hAlo = (ushort*)p;          p += (size_t)N_NODES * LDA * 2;
    float* as_  = (float*)p;            p += (size_t)N_NODES * HEADS * 4;
    float* ad_  = (float*)p;            p += (size_t)N_NODES * HEADS * 4;
    const int wsz0 = PK0 * NT_HID * 512;
    const int wszH = PKH * NT_HID * 512;
    const int wszO = PKO * NT_HEAD * 512;
    ushort* wfhi[4]; ushort* wflo[4];
    for (int l = 0; l < 4; ++l) {
        int sz = (l == 0) ? wsz0 : wszH;
        wfhi[l] = (ushort*)p; p += (size_t)sz * 2;
        wflo[l] = (ushort*)p; p += (size_t)sz * 2;
    }
    ushort* whhi = (ushort*)p; p += (size_t)wszO * 2;
    ushort* whlo = (ushort*)p; p += (size_t)wszO * 2;
    int* deg  = (int*)p;  p += N_NODES * 4;
    int* cur  = (int*)p;  p += N_NODES * 4;
    int* rowp = (int*)p;  p += (N_NODES + 1) * 4;
    int* csr  = (int*)p;  p += (size_t)TOT_E * 4;

    // ---- CSR build ----
    hipMemsetAsync(deg, 0, sizeof(int) * 2 * N_NODES, stream);  // deg + cur
    int egrid = (TOT_E + 255) / 256;
    deg_k<<<egrid, 256, 0, stream>>>(ei, deg);
    scan_k<<<1, 1024, 0, stream>>>(deg, rowp);
    fill_k<<<egrid, 256, 0, stream>>>(ei, rowp, cur, csr);

    // ---- weight + input conversion (single launch for all weights) ----
    splitx_k<<<(N_NODES * IN_CH + 255) / 256, 256, 0, stream>>>(x, hAhi);
    {
        int tot = SEG0 + 3 * SEGH + SEGO;
        convall_k<<<(tot + 255) / 256, 256, 0, stream>>>(
            W[0], W[1], W[2], W[3], Wh,
            As[0], As[1], As[2], As[3],
            Ad[0], Ad[1], Ad[2], Ad[3],
            wfhi[0], wflo[0], wfhi[1], wflo[1], wfhi[2], wflo[2],
            wfhi[3], wflo[3], whhi, whlo);
    }

    dim3 gG((N_NODES + 127) / 128, NT_HID / NTG);   // 157 x 3
    dim3 gO((N_NODES + 127) / 128, NT_HEAD / NTG);  // 157 x 2
    size_t smHid = (size_t)(8192 + 2 * NTG * 512 + 2 * 512) * 2;
    size_t smHead = (size_t)(8192 + 2 * NTG * 512 + 8192 + 2 * NTG * 512) * 2;
    int ggrid = N_NODES / 4;

    for (int l = 0; l < 4; ++l) {
        int kpairs = (l == 0) ? PK0 / 2 : PKH / 2;
        gemm4_k<false><<<gG, 256, smHid, stream>>>(hAhi, nullptr, kpairs,
                                                   wfhi[l], wflo[l], NT_HID, 2,
                                                   hBb, as_, ad_, nullptr, 0, 0, nullptr);
        gat_k<<<ggrid, 256, 0, stream>>>(hBb, as_, ad_, rowp, csr, Bb[l],
                                         hAhi, (l == 3) ? hAlo : nullptr);
    }

    // head readout (3-term) -> fp32 out [N, 132]
    gemm4_k<true><<<gO, 256, smHead, stream>>>(hAhi, hAlo, PKO / 2,
                                               whhi, whlo, NT_HEAD, -1,
                                               nullptr, nullptr, nullptr,
                                               (float*)d_out, OUTW, OUTW, bh);
}

// Round 14
// 485.697 us; speedup vs baseline: 1.2871x; 1.0247x over previous
//
#include <hip/hip_runtime.h>
#include <hip/hip_bf16.h>

#define N_NODES 20000
#define N_EDGES 320000
#define TOT_E   (N_EDGES + N_NODES)   // 340000 with self loops
#define IN_CH   128
#define HEADS   8
#define CH      33
#define DD      264                   // HEADS*CH
#define OUTW    132
#define NEG     0.2f

#define LDB     272                   // bf16 payload row stride
#define LDA     320                   // hA bf16 row stride, K padded to 10*32
#define NT_HID  18                    // 17 payload tiles + 1 stats tile [was|wad]
#define NT_HEAD 12                    // head gemm tiles (132 -> 192, zero-padded)
#define PK0     4
#define PKH     10
#define PKO     10

typedef unsigned short ushort;
typedef short bf16x8 __attribute__((ext_vector_type(8)));
typedef float f32x4  __attribute__((ext_vector_type(4)));

__device__ inline void split2(float v, ushort& hi, ushort& lo) {
    __hip_bfloat16 h = __float2bfloat16(v);
    float r = v - __bfloat162float(h);
    __hip_bfloat16 l = __float2bfloat16(r);
    hi = *(ushort*)&h;
    lo = *(ushort*)&l;
}

__device__ inline float bf2f(ushort u) {
    union { unsigned int i; float f; } c;
    c.i = ((unsigned int)u) << 16;
    return c.f;
}

// ---------------- CSR build ----------------

__global__ void deg_k(const int* __restrict__ ei, int* __restrict__ deg) {
    int e = blockIdx.x * 256 + threadIdx.x;
    if (e >= TOT_E) return;
    int dst = (e < N_EDGES) ? ei[N_EDGES + e] : (e - N_EDGES);
    atomicAdd(&deg[dst], 1);
}

__global__ __launch_bounds__(1024) void scan_k(const int* __restrict__ deg,
                                               int* __restrict__ rowp) {
    __shared__ int part[1024];
    const int PER = 20;
    int t = threadIdx.x;
    int base = t * PER;
    int s = 0;
    for (int i = 0; i < PER; ++i) {
        int idx = base + i;
        if (idx < N_NODES) s += deg[idx];
    }
    part[t] = s;
    __syncthreads();
    for (int off = 1; off < 1024; off <<= 1) {
        int v = 0;
        if (t >= off) v = part[t - off];
        __syncthreads();
        part[t] += v;
        __syncthreads();
    }
    int run = part[t] - s;
    for (int i = 0; i < PER; ++i) {
        int idx = base + i;
        if (idx < N_NODES) { rowp[idx] = run; run += deg[idx]; }
    }
    if (t == 1023) rowp[N_NODES] = part[1023];
}

__global__ void fill_k(const int* __restrict__ ei, const int* __restrict__ rowp,
                       int* __restrict__ cur, int* __restrict__ csr) {
    int e = blockIdx.x * 256 + threadIdx.x;
    if (e >= TOT_E) return;
    int src, dst;
    if (e < N_EDGES) { src = ei[e]; dst = ei[N_EDGES + e]; }
    else             { src = dst = e - N_EDGES; }
    int p = atomicAdd(&cur[dst], 1);
    csr[rowp[dst] + p] = src;
}

// ---------------- input x -> bf16 (into hAhi, stride LDA) ----------------

__global__ void splitx_k(const float* __restrict__ x, ushort* __restrict__ ahi) {
    int idx = blockIdx.x * 256 + threadIdx.x;
    if (idx >= N_NODES * IN_CH) return;
    int n = idx >> 7, k = idx & 127;
    __hip_bfloat16 h = __float2bfloat16(x[idx]);
    ahi[(size_t)n * LDA + k] = *(ushort*)&h;
}

// ---------------- all weights -> fragment-ordered hi/lo bf16, one launch ----------------

__device__ void convw_one(const float* W, const float* a_s, const float* a_d,
                          int K, int NC, int NT, ushort* fhi, ushort* flo, int gid) {
    int p = gid / (NT * 64);
    int rem = gid % (NT * 64);
    int t = rem >> 6, c = rem & 63;
    int kq = c >> 4, m = c & 15;
    int n = t * 16 + m;
    bool stats = (a_s != nullptr) && (t == NT - 1);
    ushort hi8[8], lo8[8];
#pragma unroll
    for (int j = 0; j < 8; ++j) {
        int k = p * 32 + kq * 8 + j;
        float v = 0.f;
        if (k < K) {
            if (stats) {
                const float* av = (m < 8) ? a_s : a_d;
                int h = (m < 8) ? m : m - 8;
                const float* wr = W + (size_t)k * NC + h * CH;
                float s = 0.f;
                for (int cc = 0; cc < CH; ++cc) s += wr[cc] * av[h * CH + cc];
                v = s;
            } else if (n < NC) {
                v = W[(size_t)k * NC + n];
            }
        }
        split2(v, hi8[j], lo8[j]);
    }
    size_t o = ((size_t)gid) * 8;
#pragma unroll
    for (int j = 0; j < 8; ++j) { fhi[o + j] = hi8[j]; flo[o + j] = lo8[j]; }
}

#define SEG0 (PK0 * NT_HID * 64)
#define SEGH (PKH * NT_HID * 64)
#define SEGO (PKO * NT_HEAD * 64)

__global__ void convall_k(
    const float* W0, const float* W1, const float* W2, const float* W3, const float* Wh,
    const float* as0, const float* as1, const float* as2, const float* as3,
    const float* ad0, const float* ad1, const float* ad2, const float* ad3,
    ushort* f0h, ushort* f0l, ushort* f1h, ushort* f1l, ushort* f2h, ushort* f2l,
    ushort* f3h, ushort* f3l, ushort* fhh, ushort* fhl) {
    int gid = blockIdx.x * 256 + threadIdx.x;
    if (gid < SEG0) { convw_one(W0, as0, ad0, IN_CH, DD, NT_HID, f0h, f0l, gid); return; }
    gid -= SEG0;
    if (gid < SEGH) { convw_one(W1, as1, ad1, DD, DD, NT_HID, f1h, f1l, gid); return; }
    gid -= SEGH;
    if (gid < SEGH) { convw_one(W2, as2, ad2, DD, DD, NT_HID, f2h, f2l, gid); return; }
    gid -= SEGH;
    if (gid < SEGH) { convw_one(W3, as3, ad3, DD, DD, NT_HID, f3h, f3l, gid); return; }
    gid -= SEGH;
    if (gid < SEGO) { convw_one(Wh, nullptr, nullptr, DD, OUTW, NT_HEAD, fhh, fhl, gid); }
}

// ---------------- MFMA GEMM, M=128, BK=64, swizzled A LDS, TG=6 (R12-proven) ---------
// Hidden (USE3=0): payload 1-term; stats tile (+Ahi*Wlo) at blockIdx.y==statsY, t==TG-1.
// Head (USE3=1): 3-term, fp32 C + bias.

template<bool USE3, int TG>
__global__ __launch_bounds__(256) void gemm4_k(
    const ushort* __restrict__ Ahi, const ushort* __restrict__ Alo, int kpairs,
    const ushort* __restrict__ Bhi, const ushort* __restrict__ Blo, int NTtot, int statsY,
    ushort* __restrict__ Cb16, float* __restrict__ as_, float* __restrict__ ad_,
    float* __restrict__ C, int ldc, int ncguard, const float* __restrict__ bias) {
    extern __shared__ ushort smem[];
    ushort* AlH = smem;                       // [2][8][512] = 8192 ushorts
    ushort* BlH = smem + 8192;                // [2][TG][512]
    ushort* EXT = smem + 8192 + 2 * TG * 512;
    ushort* AlL = EXT;                        // USE3
    ushort* BlL = EXT + 8192;                 // USE3
    ushort* BstL = EXT;                       // !USE3: stats-tile lo [2][512]

    int tid = threadIdx.x;
    int m0 = blockIdx.x * 128;
    int t0 = blockIdx.y * TG;
    bool sg = ((int)blockIdx.y == statsY);

    f32x4 acc[2][TG];
#pragma unroll
    for (int mt = 0; mt < 2; ++mt)
#pragma unroll
        for (int t = 0; t < TG; ++t) acc[mt][t] = (f32x4){0.f, 0.f, 0.f, 0.f};

    int w = tid >> 6, lane = tid & 63;
    int csA = (lane ^ ((lane >> 4) << 1)) * 8;

    for (int pp = 0; pp < kpairs; ++pp) {
        int nA = USE3 ? 2048 : 1024;
        for (int id = tid; id < nA; id += 256) {
            int hl = id >> 10;
            int cid = id & 1023;
            int mrow = cid >> 3, kq8 = cid & 7;
            int panel = kq8 >> 2, kq = kq8 & 3;
            int gm = m0 + mrow;
            uint4 v = {0, 0, 0, 0};
            if (gm < N_NODES) {
                const ushort* src = (hl ? Alo : Ahi) + (size_t)gm * LDA + pp * 64 + kq8 * 8;
                v = *(const uint4*)src;
            }
            int c = kq * 16 + (mrow & 15);
            int cs = c ^ ((c >> 4) << 1);
            ushort* dst = (hl ? AlL : AlH) + panel * 4096 + (mrow >> 4) * 512 + cs * 8;
            *(uint4*)dst = v;
        }
        for (int id = tid; id < 2 * TG * 64; id += 256) {
            int c = id & 63;
            int r = id >> 6;
            int t = r % TG;
            int panel = r / TG;
            const ushort* src = Bhi + ((size_t)((pp * 2 + panel) * NTtot + t0 + t) * 64 + c) * 8;
            *(uint4*)&BlH[(panel * TG + t) * 512 + c * 8] = *(const uint4*)src;
        }
        if (USE3) {
            for (int id = tid; id < 2 * TG * 64; id += 256) {
                int c = id & 63;
                int r = id >> 6;
                int t = r % TG;
                int panel = r / TG;
                const ushort* src = Blo + ((size_t)((pp * 2 + panel) * NTtot + t0 + t) * 64 + c) * 8;
                *(uint4*)&BlL[(panel * TG + t) * 512 + c * 8] = *(const uint4*)src;
            }
        } else if (sg) {
            for (int id = tid; id < 2 * 64; id += 256) {
                int c = id & 63;
                int panel = id >> 6;
                const ushort* src = Blo + ((size_t)((pp * 2 + panel) * NTtot + t0 + TG - 1) * 64 + c) * 8;
                *(uint4*)&BstL[panel * 512 + c * 8] = *(const uint4*)src;
            }
        }
        __syncthreads();

#pragma unroll
        for (int panel = 0; panel < 2; ++panel) {
            bf16x8 a0 = *(const bf16x8*)&AlH[panel * 4096 + (2 * w) * 512 + csA];
            bf16x8 a1 = *(const bf16x8*)&AlH[panel * 4096 + (2 * w + 1) * 512 + csA];
            bf16x8 l0, l1;
            if (USE3) {
                l0 = *(const bf16x8*)&AlL[panel * 4096 + (2 * w) * 512 + csA];
                l1 = *(const bf16x8*)&AlL[panel * 4096 + (2 * w + 1) * 512 + csA];
            }
#pragma unroll
            for (int t = 0; t < TG; ++t) {
                bf16x8 bh = *(const bf16x8*)&BlH[(panel * TG + t) * 512 + lane * 8];
                acc[0][t] = __builtin_amdgcn_mfma_f32_16x16x32_bf16(a0, bh, acc[0][t], 0, 0, 0);
                acc[1][t] = __builtin_amdgcn_mfma_f32_16x16x32_bf16(a1, bh, acc[1][t], 0, 0, 0);
                if (USE3) {
                    bf16x8 bl = *(const bf16x8*)&BlL[(panel * TG + t) * 512 + lane * 8];
                    acc[0][t] = __builtin_amdgcn_mfma_f32_16x16x32_bf16(a0, bl, acc[0][t], 0, 0, 0);
                    acc[1][t] = __builtin_amdgcn_mfma_f32_16x16x32_bf16(a1, bl, acc[1][t], 0, 0, 0);
                    acc[0][t] = __builtin_amdgcn_mfma_f32_16x16x32_bf16(l0, bh, acc[0][t], 0, 0, 0);
                    acc[1][t] = __builtin_amdgcn_mfma_f32_16x16x32_bf16(l1, bh, acc[1][t], 0, 0, 0);
                } else if (t == TG - 1 && sg) {
                    bf16x8 bst = *(const bf16x8*)&BstL[panel * 512 + lane * 8];
                    acc[0][t] = __builtin_amdgcn_mfma_f32_16x16x32_bf16(a0, bst, acc[0][t], 0, 0, 0);
                    acc[1][t] = __builtin_amdgcn_mfma_f32_16x16x32_bf16(a1, bst, acc[1][t], 0, 0, 0);
                }
            }
        }
        __syncthreads();
    }

    int col = lane & 15;
#pragma unroll
    for (int mt = 0; mt < 2; ++mt) {
        int rbase = m0 + (2 * w + mt) * 16 + ((lane >> 4) << 2);
#pragma unroll
        for (int t = 0; t < TG; ++t) {
            int tg = t0 + t;
#pragma unroll
            for (int r = 0; r < 4; ++r) {
                int gm = rbase + r;
                if (gm >= N_NODES) continue;
                float v = acc[mt][t][r];
                if (C) {
                    int gn = tg * 16 + col;
                    if (gn < ncguard) C[(size_t)gm * ldc + gn] = v + bias[gn];
                } else if (tg < 17) {
                    __hip_bfloat16 bv = __float2bfloat16(v);
                    Cb16[(size_t)gm * LDB + tg * 16 + col] = *(ushort*)&bv;
                } else {
                    if (col < 8) as_[(size_t)gm * 8 + col] = v;
                    else         ad_[(size_t)gm * 8 + col - 8] = v;
                }
            }
        }
    }
}

// ---------------- fused softmax + gather-aggregate: 1 wave / block (R12 logic) -------

__global__ __launch_bounds__(64) void gat_k(
    const ushort* __restrict__ xb, const float* __restrict__ as_,
    const float* __restrict__ ad_, const int* __restrict__ rowp,
    const int* __restrict__ csr, const float* __restrict__ bias,
    ushort* __restrict__ outhi, ushort* __restrict__ outlo) {
    int lane = threadIdx.x;
    int node = blockIdx.x;   // grid is exactly N
    int r0 = rowp[node], dg = rowp[node + 1] - r0;

    __shared__ float lex[64][9];
    __shared__ int   lsrc[64];

    float ad[8];
#pragma unroll
    for (int h = 0; h < 8; ++h) ad[h] = ad_[node * 8 + h];

    float mx[8], iv[8], e8[8];
    int myS = node;
    bool fast = (dg <= 64);
    if (fast) {
#pragma unroll
        for (int h = 0; h < 8; ++h) e8[h] = -1e30f;
        if (lane < dg) {
            myS = csr[r0 + lane];
            const float* ap = as_ + (size_t)myS * 8;
#pragma unroll
            for (int h = 0; h < 8; ++h) {
                float e = ap[h] + ad[h];
                e8[h] = e > 0.f ? e : NEG * e;
            }
        }
#pragma unroll
        for (int h = 0; h < 8; ++h) {
            float m = e8[h];
            for (int off = 32; off; off >>= 1) m = fmaxf(m, __shfl_xor(m, off, 64));
            mx[h] = m;
        }
#pragma unroll
        for (int h = 0; h < 8; ++h) {
            float ex = (lane < dg) ? __expf(e8[h] - mx[h]) : 0.f;
            e8[h] = ex;
            float s = ex;
            for (int off = 32; off; off >>= 1) s += __shfl_xor(s, off, 64);
            iv[h] = 1.0f / (s + 1e-16f);
        }
    } else {
#pragma unroll
        for (int h = 0; h < 8; ++h) mx[h] = -1e30f;
        for (int j = lane; j < dg; j += 64) {
            int s = csr[r0 + j];
            const float* ap = as_ + (size_t)s * 8;
#pragma unroll
            for (int h = 0; h < 8; ++h) {
                float e = ap[h] + ad[h];
                e = e > 0.f ? e : NEG * e;
                mx[h] = fmaxf(mx[h], e);
            }
        }
#pragma unroll
        for (int h = 0; h < 8; ++h)
            for (int off = 32; off; off >>= 1)
                mx[h] = fmaxf(mx[h], __shfl_xor(mx[h], off, 64));
        float sm[8] = {0.f, 0.f, 0.f, 0.f, 0.f, 0.f, 0.f, 0.f};
        for (int j = lane; j < dg; j += 64) {
            int s = csr[r0 + j];
            const float* ap = as_ + (size_t)s * 8;
#pragma unroll
            for (int h = 0; h < 8; ++h) {
                float e = ap[h] + ad[h];
                e = e > 0.f ? e : NEG * e;
                sm[h] += __expf(e - mx[h]);
            }
        }
#pragma unroll
        for (int h = 0; h < 8; ++h) {
            for (int off = 32; off; off >>= 1) sm[h] += __shfl_xor(sm[h], off, 64);
            iv[h] = 1.0f / (sm[h] + 1e-16f);
        }
    }

    int h0[4], h1[4];
#pragma unroll
    for (int j = 0; j < 4; ++j) {
        h0[j] = (4 * lane + j) / 33;
        h1[j] = (4 * (lane + 64) + j) / 33;
    }
    float4 a0 = {0.f, 0.f, 0.f, 0.f}, a1 = {0.f, 0.f, 0.f, 0.f};

    int nchunks = (dg + 63) >> 6;
    for (int c = 0; c < nchunks; ++c) {
        int base = c << 6, j = base + lane;
        int s = node;
        float al[8];
#pragma unroll
        for (int h = 0; h < 8; ++h) al[h] = 0.f;
        if (j < dg) {
            if (fast) {
                s = myS;
#pragma unroll
                for (int h = 0; h < 8; ++h) al[h] = e8[h] * iv[h];
            } else {
                s = csr[r0 + j];
                const float* ap = as_ + (size_t)s * 8;
#pragma unroll
                for (int h = 0; h < 8; ++h) {
                    float e = ap[h] + ad[h];
                    e = e > 0.f ? e : NEG * e;
                    al[h] = __expf(e - mx[h]) * iv[h];
                }
            }
        }
        lsrc[lane] = s;
#pragma unroll
        for (int h = 0; h < 8; ++h) lex[lane][h] = al[h];
        __builtin_amdgcn_wave_barrier();

        int rem = dg - base;
        int cnt = rem > 64 ? 64 : rem;
        int cnt4 = (cnt + 3) & ~3;
        for (int jj = 0; jj < cnt4; jj += 4) {
            int s0 = lsrc[jj + 0], s1 = lsrc[jj + 1];
            int s2 = lsrc[jj + 2], s3 = lsrc[jj + 3];
            const ushort4* p0 = (const ushort4*)(xb + (size_t)s0 * LDB);
            const ushort4* p1 = (const ushort4*)(xb + (size_t)s1 * LDB);
            const ushort4* p2 = (const ushort4*)(xb + (size_t)s2 * LDB);
            const ushort4* p3 = (const ushort4*)(xb + (size_t)s3 * LDB);
            ushort4 v0 = p0[lane], v1 = p1[lane], v2 = p2[lane], v3 = p3[lane];
            ushort4 w0, w1, w2, w3;
            if (lane < 2) { w0 = p0[64 + lane]; w1 = p1[64 + lane]; w2 = p2[64 + lane]; w3 = p3[64 + lane]; }
            const float* x0 = lex[jj + 0];
            const float* x1 = lex[jj + 1];
            const float* x2 = lex[jj + 2];
            const float* x3 = lex[jj + 3];
            a0.x += x0[h0[0]] * bf2f(v0.x) + x1[h0[0]] * bf2f(v1.x)
                  + x2[h0[0]] * bf2f(v2.x) + x3[h0[0]] * bf2f(v3.x);
            a0.y += x0[h0[1]] * bf2f(v0.y) + x1[h0[1]] * bf2f(v1.y)
                  + x2[h0[1]] * bf2f(v2.y) + x3[h0[1]] * bf2f(v3.y);
            a0.z += x0[h0[2]] * bf2f(v0.z) + x1[h0[2]] * bf2f(v1.z)
                  + x2[h0[2]] * bf2f(v2.z) + x3[h0[2]] * bf2f(v3.z);
            a0.w += x0[h0[3]] * bf2f(v0.w) + x1[h0[3]] * bf2f(v1.w)
                  + x2[h0[3]] * bf2f(v2.w) + x3[h0[3]] * bf2f(v3.w);
            if (lane < 2) {
                a1.x += x0[h1[0]] * bf2f(w0.x) + x1[h1[0]] * bf2f(w1.x)
                      + x2[h1[0]] * bf2f(w2.x) + x3[h1[0]] * bf2f(w3.x);
                a1.y += x0[h1[1]] * bf2f(w0.y) + x1[h1[1]] * bf2f(w1.y)
                      + x2[h1[1]] * bf2f(w2.y) + x3[h1[1]] * bf2f(w3.y);
                a1.z += x0[h1[2]] * bf2f(w0.z) + x1[h1[2]] * bf2f(w1.z)
                      + x2[h1[2]] * bf2f(w2.z) + x3[h1[2]] * bf2f(w3.z);
                a1.w += x0[h1[3]] * bf2f(w0.w) + x1[h1[3]] * bf2f(w1.w)
                      + x2[h1[3]] * bf2f(w2.w) + x3[h1[3]] * bf2f(w3.w);
            }
        }
        __builtin_amdgcn_wave_barrier();
    }

    // epilogue: bias + elu, bf16 (hi) out; lo only when requested; zero K-pad to LDA
#pragma unroll
    for (int k = 0; k < 2; ++k) {
        int i4 = lane + 64 * k;
        if (i4 < 66) {
            float4 a = (k == 0) ? a0 : a1;
            float vals[4] = {a.x, a.y, a.z, a.w};
            ushort hi4[4], lo4[4];
#pragma unroll
            for (int j = 0; j < 4; ++j) {
                float v = vals[j] + bias[i4 * 4 + j];
                v = v > 0.f ? v : (__expf(v) - 1.f);
                split2(v, hi4[j], lo4[j]);
            }
            size_t o = (size_t)node * LDA + i4 * 4;
            *(ushort4*)(outhi + o) = *(ushort4*)hi4;
            if (outlo) *(ushort4*)(outlo + o) = *(ushort4*)lo4;
        } else if (i4 < 80) {
            ushort4 z = {0, 0, 0, 0};
            size_t o = (size_t)node * LDA + i4 * 4;
            *(ushort4*)(outhi + o) = z;
            if (outlo) *(ushort4*)(outlo + o) = z;
        }
    }
}

// ---------------- launch ----------------

extern "C" void kernel_launch(void* const* d_in, const int* in_sizes, int n_in,
                              void* d_out, int out_size, void* d_ws, size_t ws_size,
                              hipStream_t stream) {
    const float* x  = (const float*)d_in[0];
    const int*   ei = (const int*)d_in[1];
    const float* W[4]  = {(const float*)d_in[2],  (const float*)d_in[6],
                          (const float*)d_in[10], (const float*)d_in[14]};
    const float* As[4] = {(const float*)d_in[3],  (const float*)d_in[7],
                          (const float*)d_in[11], (const float*)d_in[15]};
    const float* Ad[4] = {(const float*)d_in[4],  (const float*)d_in[8],
                          (const float*)d_in[12], (const float*)d_in[16]};
    const float* Bb[4] = {(const float*)d_in[5],  (const float*)d_in[9],
                          (const float*)d_in[13], (const float*)d_in[17]};
    const float* Wh = (const float*)d_in[18];
    const float* bh = (const float*)d_in[19];

    // ---- workspace carve ----
    char* p = (char*)d_ws;
    ushort* hBb  = (ushort*)p;          p += (size_t)N_NODES * LDB * 2;
    ushort* hAhi = (ushort*)p;          p += (size_t)N_NODES * LDA * 2;
    ushort* hAlo = (ushort*)p;          p += (size_t)N_NODES * LDA * 2;
    float* as_  = (float*)p;            p += (size_t)N_NODES * HEADS * 4;
    float* ad_  = (float*)p;            p += (size_t)N_NODES * HEADS * 4;
    const int wsz0 = PK0 * NT_HID * 512;
    const int wszH = PKH * NT_HID * 512;
    const int wszO = PKO * NT_HEAD * 512;
    ushort* wfhi[4]; ushort* wflo[4];
    for (int l = 0; l < 4; ++l) {
        int sz = (l == 0) ? wsz0 : wszH;
        wfhi[l] = (ushort*)p; p += (size_t)sz * 2;
        wflo[l] = (ushort*)p; p += (size_t)sz * 2;
    }
    ushort* whhi = (ushort*)p; p += (size_t)wszO * 2;
    ushort* whlo = (ushort*)p; p += (size_t)wszO * 2;
    int* deg  = (int*)p;  p += N_NODES * 4;
    int* cur  = (int*)p;  p += N_NODES * 4;
    int* rowp = (int*)p;  p += (N_NODES + 1) * 4;
    int* csr  = (int*)p;  p += (size_t)TOT_E * 4;

    // ---- CSR build ----
    hipMemsetAsync(deg, 0, sizeof(int) * 2 * N_NODES, stream);  // deg + cur
    int egrid = (TOT_E + 255) / 256;
    deg_k<<<egrid, 256, 0, stream>>>(ei, deg);
    scan_k<<<1, 1024, 0, stream>>>(deg, rowp);
    fill_k<<<egrid, 256, 0, stream>>>(ei, rowp, cur, csr);

    // ---- weight + input conversion (single launch for all weights) ----
    splitx_k<<<(N_NODES * IN_CH + 255) / 256, 256, 0, stream>>>(x, hAhi);
    {
        int tot = SEG0 + 3 * SEGH + SEGO;
        convall_k<<<(tot + 255) / 256, 256, 0, stream>>>(
            W[0], W[1], W[2], W[3], Wh,
            As[0], As[1], As[2], As[3],
            Ad[0], Ad[1], Ad[2], Ad[3],
            wfhi[0], wflo[0], wfhi[1], wflo[1], wfhi[2], wflo[2],
            wfhi[3], wflo[3], whhi, whlo);
    }

    dim3 gG((N_NODES + 127) / 128, NT_HID / 6);   // 157 x 3
    dim3 gO((N_NODES + 127) / 128, NT_HEAD / 6);  // 157 x 2
    size_t smHid = (size_t)(8192 + 2 * 6 * 512 + 2 * 512) * 2;             // 30720 B
    size_t smHead = (size_t)(8192 + 2 * 6 * 512 + 8192 + 2 * 6 * 512) * 2; // 57344 B

    for (int l = 0; l < 4; ++l) {
        int kpairs = (l == 0) ? PK0 / 2 : PKH / 2;
        gemm4_k<false, 6><<<gG, 256, smHid, stream>>>(hAhi, nullptr, kpairs,
                                                      wfhi[l], wflo[l], NT_HID, 2,
                                                      hBb, as_, ad_, nullptr, 0, 0, nullptr);
        gat_k<<<N_NODES, 64, 0, stream>>>(hBb, as_, ad_, rowp, csr, Bb[l],
                                          hAhi, (l == 3) ? hAlo : nullptr);
    }

    // head readout (3-term) -> fp32 out [N, 132]
    gemm4_k<true, 6><<<gO, 256, smHead, stream>>>(hAhi, hAlo, PKO / 2,
                                                  whhi, whlo, NT_HEAD, -1,
                                                  nullptr, nullptr, nullptr,
                                                  (float*)d_out, OUTW, OUTW, bh);
}